// Round 5
// baseline (912.554 us; speedup 1.0000x reference)
//
#include <hip/hip_runtime.h>
#include <hip/hip_bf16.h>

#define NC 8192
#define NF 16384
#define NE 262144
#define TROW 8000   // 125 * 64
#define GB 8
#define NCELL 512   // GB^3
#define CELLH 0.125f

typedef __attribute__((ext_vector_type(8))) short short8v;  // 8 bf16
typedef __attribute__((ext_vector_type(4))) float f32x4;

// ---------------- binning: histogram ----------------
__global__ __launch_bounds__(256) void bin_hist_kernel(
    const float* __restrict__ pos, int* __restrict__ cellCnt, int* __restrict__ cellId)
{
    const int i = blockIdx.x * 256 + threadIdx.x;   // NC threads
    const float px = pos[i*3+0], py = pos[i*3+1], pz = pos[i*3+2];
    const int cx = min((int)(px * GB), GB-1);
    const int cy = min((int)(py * GB), GB-1);
    const int cz = min((int)(pz * GB), GB-1);
    const int cell = (cz*GB + cy)*GB + cx;
    cellId[i] = cell;
    atomicAdd(&cellCnt[cell], 1);
}

// ---------------- binning: scan 512 cells ----------------
__global__ __launch_bounds__(512) void bin_scan_kernel(
    const int* __restrict__ cellCnt, int* __restrict__ cellOffs, int* __restrict__ cellCursor)
{
    __shared__ int s[512];
    const int tid = threadIdx.x;
    const int v = cellCnt[tid];
    s[tid] = v;
    __syncthreads();
    for (int off = 1; off < 512; off <<= 1) {
        int t = (tid >= off) ? s[tid - off] : 0;
        __syncthreads();
        s[tid] += t;
        __syncthreads();
    }
    cellOffs[tid] = s[tid] - v;
    cellCursor[tid] = s[tid] - v;
    if (tid == 511) cellOffs[512] = s[511];
}

// ---------------- binning: scatter points (gathered pos/batch copies) ----------------
__global__ __launch_bounds__(256) void bin_scatter_kernel(
    const float* __restrict__ pos, const int* __restrict__ batch,
    const int* __restrict__ cellId, int* __restrict__ cellCursor,
    int* __restrict__ binPts, float* __restrict__ binPos, int* __restrict__ binBatch)
{
    const int i = blockIdx.x * 256 + threadIdx.x;
    const int cell = cellId[i];
    const int p = atomicAdd(&cellCursor[cell], 1);
    binPts[p] = i;
    binPos[p*3+0] = pos[i*3+0];
    binPos[p*3+1] = pos[i*3+1];
    binPos[p*3+2] = pos[i*3+2];
    binBatch[p] = batch[i];
}

// ---------------- KNN query: 4 lanes per query over 27-cell neighborhood ----------------
__global__ __launch_bounds__(256) void knn_query_kernel(
    const float* __restrict__ binPos, const int* __restrict__ binPts,
    const int* __restrict__ binBatch, const int* __restrict__ cellOffs,
    const float* __restrict__ pos_skip, const int* __restrict__ batch_skip,
    int* __restrict__ idx3, float* __restrict__ w3, int* __restrict__ flags)
{
    const int tid = threadIdx.x;
    const int sub = tid & 3;
    const int y = blockIdx.x * 64 + (tid >> 2);
    const float px = pos_skip[y*3+0], py = pos_skip[y*3+1], pz = pos_skip[y*3+2];
    const int by = batch_skip[y];
    const int cx = min((int)(px * GB), GB-1);
    const int cy = min((int)(py * GB), GB-1);
    const int cz = min((int)(pz * GB), GB-1);
    float b0 = INFINITY, b1 = INFINITY, b2 = INFINITY;
    int i0 = 0, i1 = 0, i2 = 0;
    auto ins = [&](float d, int gj) {
        if (d < b2) {
            if (d < b1) {
                b2 = b1; i2 = i1;
                if (d < b0) { b1 = b0; i1 = i0; b0 = d; i0 = gj; }
                else        { b1 = d;  i1 = gj; }
            } else { b2 = d; i2 = gj; }
        }
    };
    int cidx = 0;
    const int zlo = max(cz-1, 0), zhi = min(cz+1, GB-1);
    const int ylo = max(cy-1, 0), yhi = min(cy+1, GB-1);
    const int xlo = max(cx-1, 0), xhi = min(cx+1, GB-1);
    for (int zz = zlo; zz <= zhi; ++zz)
    for (int yy = ylo; yy <= yhi; ++yy)
    for (int xx = xlo; xx <= xhi; ++xx) {
        if ((cidx++ & 3) != sub) continue;
        const int cell = (zz*GB + yy)*GB + xx;
        const int pEnd = cellOffs[cell+1];
        for (int p = cellOffs[cell]; p < pEnd; ++p) {
            const float dx = px - binPos[p*3+0];
            const float dy = py - binPos[p*3+1];
            const float dz = pz - binPos[p*3+2];
            float d = dx*dx + dy*dy + dz*dz;
            if (binBatch[p] != by) d = INFINITY;
            ins(d, binPts[p]);
        }
    }
    // merge across 4 split lanes
    #pragma unroll
    for (int mask = 1; mask <= 2; mask <<= 1) {
        float c0 = __shfl_xor(b0, mask), c1 = __shfl_xor(b1, mask), c2 = __shfl_xor(b2, mask);
        int   j0 = __shfl_xor(i0, mask), j1 = __shfl_xor(i1, mask), j2 = __shfl_xor(i2, mask);
        ins(c0, j0); ins(c1, j1); ins(c2, j2);
    }
    if (sub == 0) {
        // exactness: 3rd-best must be within the searched box (cube faces exempt)
        float rd = 1e30f;
        if (cx > 0)    rd = fminf(rd, px - (cx-1)*CELLH);
        if (cx < GB-1) rd = fminf(rd, (cx+2)*CELLH - px);
        if (cy > 0)    rd = fminf(rd, py - (cy-1)*CELLH);
        if (cy < GB-1) rd = fminf(rd, (cy+2)*CELLH - py);
        if (cz > 0)    rd = fminf(rd, pz - (cz-1)*CELLH);
        if (cz < GB-1) rd = fminf(rd, (cz+2)*CELLH - pz);
        if (!(b2 <= rd*rd)) flags[y] = 1;   // also catches b2 == INF
        idx3[y*3+0] = i0; idx3[y*3+1] = i1; idx3[y*3+2] = i2;
        w3[y*3+0] = 1.0f / fmaxf(b0, 1e-16f);
        w3[y*3+1] = 1.0f / fmaxf(b1, 1e-16f);
        w3[y*3+2] = 1.0f / fmaxf(b2, 1e-16f);
    }
}

// ---------------- KNN fallback: exact brute force for flagged queries ----------------
__global__ __launch_bounds__(256) void knn_fallback_kernel(
    const float* __restrict__ pos, const int* __restrict__ batch,
    const float* __restrict__ pos_skip, const int* __restrict__ batch_skip,
    const int* __restrict__ flags, int* __restrict__ idx3, float* __restrict__ w3)
{
    const int s = threadIdx.x & 63;
    const int y = blockIdx.x * 4 + (threadIdx.x >> 6);
    if (!flags[y]) return;   // wave-uniform
    const float px = pos_skip[y*3+0], py = pos_skip[y*3+1], pz = pos_skip[y*3+2];
    const int by = batch_skip[y];
    float b0 = INFINITY, b1 = INFINITY, b2 = INFINITY;
    int i0 = 0, i1 = 0, i2 = 0;
    auto ins = [&](float d, int gj) {
        if (d < b2) {
            if (d < b1) {
                b2 = b1; i2 = i1;
                if (d < b0) { b1 = b0; i1 = i0; b0 = d; i0 = gj; }
                else        { b1 = d;  i1 = gj; }
            } else { b2 = d; i2 = gj; }
        }
    };
    for (int j = s; j < NC; j += 64) {
        const float dx = px - pos[j*3+0];
        const float dy = py - pos[j*3+1];
        const float dz = pz - pos[j*3+2];
        float d = dx*dx + dy*dy + dz*dz;
        if (batch[j] != by) d = INFINITY;
        ins(d, j);
    }
    #pragma unroll
    for (int mask = 1; mask <= 32; mask <<= 1) {
        float c0 = __shfl_xor(b0, mask), c1 = __shfl_xor(b1, mask), c2 = __shfl_xor(b2, mask);
        int   j0 = __shfl_xor(i0, mask), j1 = __shfl_xor(i1, mask), j2 = __shfl_xor(i2, mask);
        ins(c0, j0); ins(c1, j1); ins(c2, j2);
    }
    if (s == 0) {
        idx3[y*3+0] = i0; idx3[y*3+1] = i1; idx3[y*3+2] = i2;
        w3[y*3+0] = 1.0f / fmaxf(b0, 1e-16f);
        w3[y*3+1] = 1.0f / fmaxf(b1, 1e-16f);
        w3[y*3+2] = 1.0f / fmaxf(b2, 1e-16f);
    }
}

// ---------------- interpolate + concat -> X0 [NF,128] fp32 ----------------
__global__ __launch_bounds__(64) void interp_kernel(
    const float* __restrict__ x, const float* __restrict__ x_skip,
    const int* __restrict__ idx3, const float* __restrict__ w3,
    float* __restrict__ X0)
{
    const int n = blockIdx.x, c = threadIdx.x;
    const int j0 = idx3[n*3+0], j1 = idx3[n*3+1], j2 = idx3[n*3+2];
    const float w0 = w3[n*3+0], w1 = w3[n*3+1], w2 = w3[n*3+2];
    const float inv = 1.0f / (w0 + w1 + w2);
    X0[(size_t)n*128 + c]      = (w0 * x[j0*64+c] + w1 * x[j1*64+c] + w2 * x[j2*64+c]) * inv;
    X0[(size_t)n*128 + 64 + c] = x_skip[n*64+c];
}

// ---------------- spline basis per edge + src/dst histograms ----------------
__global__ __launch_bounds__(256) void basis_kernel(
    const int* __restrict__ ei, const float* __restrict__ pos_skip,
    float* __restrict__ basis, uint2* __restrict__ wi8,
    int* __restrict__ cntD, int* __restrict__ cntS)
{
    const int e = blockIdx.x * 256 + threadIdx.x;
    const int src = ei[e], dst = ei[NE + e];
    float fr[3]; int lo[3];
    #pragma unroll
    for (int d = 0; d < 3; ++d) {
        float p = (pos_skip[dst*3+d] - pos_skip[src*3+d]) * 4.0f + 0.5f;
        p = fminf(fmaxf(p, 0.0f), 1.0f);
        float v = p * 4.0f;
        float l = fminf(floorf(v), 3.0f);
        fr[d] = v - l;
        lo[d] = (int)l;
    }
    unsigned int wlo = 0, whi = 0;
    #pragma unroll
    for (int s = 0; s < 8; ++s) {
        const int bit0 = s & 1, bit1 = (s >> 1) & 1, bit2 = (s >> 2) & 1;
        float b = (bit0 ? fr[0] : 1.0f - fr[0])
                * (bit1 ? fr[1] : 1.0f - fr[1])
                * (bit2 ? fr[2] : 1.0f - fr[2]);
        int w = (lo[0] + bit0) + 5 * (lo[1] + bit1) + 25 * (lo[2] + bit2);
        basis[(size_t)e*8 + s] = b;
        if (s < 4) wlo |= ((unsigned)w) << (8*s);
        else       whi |= ((unsigned)w) << (8*(s-4));
    }
    wi8[e] = make_uint2(wlo, whi);
    atomicAdd(&cntD[dst], 1);
    atomicAdd(&cntS[src], 1);
}

// ---------------- dual exclusive scan (block 0: D, block 1: S) ----------------
__global__ __launch_bounds__(1024) void scan2_kernel(
    const int* __restrict__ cntD, int* __restrict__ offsD, int* __restrict__ curD,
    const int* __restrict__ cntS, int* __restrict__ offsS, int* __restrict__ curS)
{
    const int* cnt = blockIdx.x ? cntS : cntD;
    int* offs   = blockIdx.x ? offsS : offsD;
    int* cursor = blockIdx.x ? curS  : curD;
    __shared__ int s[1024];
    __shared__ int carry_s;
    const int tid = threadIdx.x;
    if (tid == 0) carry_s = 0;
    __syncthreads();
    for (int ch = 0; ch < NF/1024; ++ch) {
        const int i = ch*1024 + tid;
        const int v = cnt[i];
        s[tid] = v;
        __syncthreads();
        for (int off = 1; off < 1024; off <<= 1) {
            int t = (tid >= off) ? s[tid - off] : 0;
            __syncthreads();
            s[tid] += t;
            __syncthreads();
        }
        const int incl  = s[tid];
        const int total = s[1023];
        const int base  = carry_s;
        const int excl  = base + incl - v;
        offs[i] = excl; cursor[i] = excl;
        __syncthreads();
        if (tid == 0) carry_s = base + total;
        __syncthreads();
    }
    if (tid == 0) offs[NF] = carry_s;
}

// ---------------- dual scatter: y=0 dst-sorted, y=1 src-sorted ----------------
__global__ __launch_bounds__(256) void scatter2_kernel(
    const int* __restrict__ ei, int* __restrict__ curD, int* __restrict__ permD,
    int* __restrict__ curS, int* __restrict__ permS)
{
    const int e = blockIdx.x * 256 + threadIdx.x;
    if (blockIdx.y == 0) {
        const int p = atomicAdd(&curD[ei[NE + e]], 1);
        permD[p] = e;
    } else {
        const int p = atomicAdd(&curS[ei[e]], 1);
        permS[p] = e;
    }
}

// ---------------- W prep: [125][KIN][64] fp32 -> Wt [125][64][KIN] bf16 ----------------
template<int KIN>
__global__ __launch_bounds__(256) void wprep_kernel(
    const float* __restrict__ W, __hip_bfloat16* __restrict__ Wt)
{
    __shared__ float s[KIN*64];
    const int kern = blockIdx.x;
    const float* Wk = W + (size_t)kern * KIN * 64;
    for (int i = threadIdx.x; i < KIN*64; i += 256) s[i] = Wk[i];
    __syncthreads();
    for (int i = threadIdx.x; i < 64*(KIN/8); i += 256) {
        const int o = i / (KIN/8), kb = (i % (KIN/8)) * 8;
        union { short8v v; __hip_bfloat16 h[8]; } u;
        #pragma unroll
        for (int j = 0; j < 8; ++j) u.h[j] = __float2bfloat16(s[(kb+j)*64 + o]);
        *(short8v*)&Wt[((size_t)kern*64 + o)*KIN + kb] = u.v;
    }
}

// ---------------- T = X @ W (bf16 MFMA; fp32 X staged with on-the-fly convert) ----------------
template<int KIN>
__global__ __launch_bounds__(256) void gemm_mfma_kernel(
    const float* __restrict__ X,             // [*, KIN] fp32, chunk base pre-offset
    const __hip_bfloat16* __restrict__ Wt,   // [125][64][KIN]
    __hip_bfloat16* __restrict__ T)          // [*, 8000]
{
    constexpr int BKP = KIN + 8;
    __shared__ __hip_bfloat16 As[128*BKP];
    __shared__ __hip_bfloat16 Bs[64*BKP];
    const int kern = blockIdx.x;
    const int m0   = blockIdx.y * 128;

    for (int i = threadIdx.x; i < 128*(KIN/8); i += 256) {
        const int r = i / (KIN/8), c8 = (i % (KIN/8)) * 8;
        const float* xp = &X[(size_t)(m0 + r)*KIN + c8];
        const float4 v0 = *(const float4*)xp;
        const float4 v1 = *(const float4*)(xp + 4);
        union { short8v v; __hip_bfloat16 h[8]; } u;
        u.h[0] = __float2bfloat16(v0.x); u.h[1] = __float2bfloat16(v0.y);
        u.h[2] = __float2bfloat16(v0.z); u.h[3] = __float2bfloat16(v0.w);
        u.h[4] = __float2bfloat16(v1.x); u.h[5] = __float2bfloat16(v1.y);
        u.h[6] = __float2bfloat16(v1.z); u.h[7] = __float2bfloat16(v1.w);
        *(short8v*)&As[r*BKP + c8] = u.v;
    }
    const __hip_bfloat16* Wk = Wt + (size_t)kern * 64 * KIN;
    for (int i = threadIdx.x; i < 64*(KIN/8); i += 256) {
        const int r = i / (KIN/8), c8 = (i % (KIN/8)) * 8;
        *(short8v*)&Bs[r*BKP + c8] = *(const short8v*)&Wk[(size_t)r*KIN + c8];
    }
    __syncthreads();

    const int wid  = threadIdx.x >> 6;
    const int lane = threadIdx.x & 63;
    const int lr   = lane & 15;
    const int lk   = (lane >> 4) * 8;

    f32x4 acc[2][4] = {};
    #pragma unroll
    for (int ks = 0; ks < KIN/32; ++ks) {
        short8v a0 = *(const short8v*)&As[(wid*32 +      lr)*BKP + ks*32 + lk];
        short8v a1 = *(const short8v*)&As[(wid*32 + 16 + lr)*BKP + ks*32 + lk];
        #pragma unroll
        for (int n = 0; n < 4; ++n) {
            short8v b = *(const short8v*)&Bs[(n*16 + lr)*BKP + ks*32 + lk];
            acc[0][n] = __builtin_amdgcn_mfma_f32_16x16x32_bf16(a0, b, acc[0][n], 0, 0, 0);
            acc[1][n] = __builtin_amdgcn_mfma_f32_16x16x32_bf16(a1, b, acc[1][n], 0, 0, 0);
        }
    }

    const int colBase = kern*64;
    #pragma unroll
    for (int m = 0; m < 2; ++m) {
        const int row = m0 + wid*32 + m*16 + (lane >> 4)*4;
        #pragma unroll
        for (int n = 0; n < 4; ++n) {
            const int col = colBase + n*16 + lr;
            #pragma unroll
            for (int i = 0; i < 4; ++i)
                T[(size_t)(row + i)*TROW + col] = __float2bfloat16(acc[m][n][i]);
        }
    }
}

// ---------------- FUSED: per-dst gather from T + mean + root + bias + ELU ----------------
template<int KIN>
__global__ __launch_bounds__(64) void agg_fused_kernel(
    const __hip_bfloat16* __restrict__ T, const float* __restrict__ basis,
    const uint2* __restrict__ wi8, const int* __restrict__ permD,
    const int* __restrict__ offsD, const int* __restrict__ cntD,
    const int* __restrict__ esrc,
    const float* __restrict__ X, const float* __restrict__ root,
    const float* __restrict__ bias, float* __restrict__ Xout)
{
    const int n = blockIdx.x, c = threadIdx.x;
    float acc = 0.0f;
    const int beg = offsD[n], num = cntD[n];
    for (int t = 0; t < num; ++t) {
        const int e = permD[beg + t];
        const int src = esrc[e];
        const uint2 w8 = wi8[e];
        const float4 bl = *(const float4*)(basis + (size_t)e*8);
        const float4 bh = *(const float4*)(basis + (size_t)e*8 + 4);
        const __hip_bfloat16* Trow = T + (size_t)src * TROW;
        acc += bl.x * __bfloat162float(Trow[((w8.x      ) & 255)*64 + c]);
        acc += bl.y * __bfloat162float(Trow[((w8.x >>  8) & 255)*64 + c]);
        acc += bl.z * __bfloat162float(Trow[((w8.x >> 16) & 255)*64 + c]);
        acc += bl.w * __bfloat162float(Trow[((w8.x >> 24) & 255)*64 + c]);
        acc += bh.x * __bfloat162float(Trow[((w8.y      ) & 255)*64 + c]);
        acc += bh.y * __bfloat162float(Trow[((w8.y >>  8) & 255)*64 + c]);
        acc += bh.z * __bfloat162float(Trow[((w8.y >> 16) & 255)*64 + c]);
        acc += bh.w * __bfloat162float(Trow[((w8.y >> 24) & 255)*64 + c]);
    }
    const float agg = acc / fmaxf((float)num, 1.0f);
    const float* xr = X + (size_t)n * KIN;
    float r = 0.0f;
    #pragma unroll 16
    for (int i = 0; i < KIN; ++i) r = fmaf(xr[i], root[i*64 + c], r);
    float o = agg + r + bias[c];
    o = (o > 0.0f) ? o : expm1f(o);
    Xout[(size_t)n*64 + c] = o;
}

// ---------------- fallback path kernels (chunked T): per-edge msg, then agg ----------------
__global__ __launch_bounds__(256) void msg_kernel(
    const __hip_bfloat16* __restrict__ Tc, int n0,
    const float* __restrict__ basis, const uint2* __restrict__ wi8,
    const int* __restrict__ permS, const int* __restrict__ offsS,
    int c0, int c1, const int* __restrict__ esrc,
    __hip_bfloat16* __restrict__ msg)
{
    const int eBeg = offsS[c0];
    const int eEnd = offsS[c1];
    const int lane = threadIdx.x & 63;
    const int sub  = threadIdx.x >> 6;
    for (int p = eBeg + blockIdx.x*4 + sub; p < eEnd; p += gridDim.x*4) {
        const int e = permS[p];
        const int src = esrc[e];
        const uint2 w8 = wi8[e];
        const float* bs = basis + (size_t)e*8;
        const __hip_bfloat16* Trow = Tc + (size_t)(src - n0) * TROW;
        float acc = 0.0f;
        #pragma unroll
        for (int s = 0; s < 4; ++s) {
            const int wk = (w8.x >> (8*s)) & 255;
            acc += bs[s] * __bfloat162float(Trow[wk*64 + lane]);
        }
        #pragma unroll
        for (int s = 0; s < 4; ++s) {
            const int wk = (w8.y >> (8*s)) & 255;
            acc += bs[4+s] * __bfloat162float(Trow[wk*64 + lane]);
        }
        msg[(size_t)e*64 + lane] = __float2bfloat16(acc);
    }
}

template<int KIN>
__global__ __launch_bounds__(64) void agg_msg_kernel(
    const __hip_bfloat16* __restrict__ msg, const int* __restrict__ permD,
    const int* __restrict__ offsD, const int* __restrict__ cntD,
    const float* __restrict__ X, const float* __restrict__ root,
    const float* __restrict__ bias, float* __restrict__ Xout)
{
    const int n = blockIdx.x, c = threadIdx.x;
    float acc = 0.0f;
    const int beg = offsD[n], num = cntD[n];
    for (int t = 0; t < num; ++t) {
        const int e = permD[beg + t];
        acc += __bfloat162float(msg[(size_t)e*64 + c]);
    }
    const float agg = acc / fmaxf((float)num, 1.0f);
    const float* xr = X + (size_t)n * KIN;
    float r = 0.0f;
    #pragma unroll 16
    for (int i = 0; i < KIN; ++i) r = fmaf(xr[i], root[i*64 + c], r);
    float o = agg + r + bias[c];
    o = (o > 0.0f) ? o : expm1f(o);
    Xout[(size_t)n*64 + c] = o;
}

// ---------------- tail: pos_skip + batch_skip passthrough ----------------
__global__ __launch_bounds__(256) void tail_kernel(
    const float* __restrict__ pos_skip, const int* __restrict__ batch_skip,
    float* __restrict__ out)
{
    const int i = blockIdx.x * 256 + threadIdx.x;
    if (i < NF*3) out[1048576 + i] = pos_skip[i];
    if (i < NF)   ((int*)out)[1048576 + NF*3 + i] = batch_skip[i];
}

extern "C" void kernel_launch(void* const* d_in, const int* in_sizes, int n_in,
                              void* d_out, int out_size, void* d_ws, size_t ws_size,
                              hipStream_t stream)
{
    const float* x          = (const float*)d_in[0];
    const float* pos        = (const float*)d_in[1];
    const int*   batch      = (const int*)d_in[2];
    const float* x_skip     = (const float*)d_in[3];
    const float* pos_skip   = (const float*)d_in[4];
    const int*   batch_skip = (const int*)d_in[5];
    const int*   ei         = (const int*)d_in[6];
    const float* W0    = (const float*)d_in[7];
    const float* root0 = (const float*)d_in[8];
    const float* b0    = (const float*)d_in[9];
    const float* W1    = (const float*)d_in[10];
    const float* root1 = (const float*)d_in[11];
    const float* b1    = (const float*)d_in[12];
    const float* W2    = (const float*)d_in[13];
    const float* root2 = (const float*)d_in[14];
    const float* b2    = (const float*)d_in[15];

    char* wp = (char*)d_ws;
    size_t used = 0;
    auto carve = [&](size_t bytes) {
        char* p = wp;
        size_t a = (bytes + 255) & ~(size_t)255;
        wp += a; used += a;
        return p;
    };
    float* X0    = (float*)carve((size_t)NF * 128 * 4);
    float* X1    = (float*)carve((size_t)NF * 64 * 4);
    float* X2    = (float*)carve((size_t)NF * 64 * 4);
    __hip_bfloat16* Wt0 = (__hip_bfloat16*)carve((size_t)125 * 128 * 64 * 2);
    __hip_bfloat16* Wt1 = (__hip_bfloat16*)carve((size_t)125 * 64 * 64 * 2);
    __hip_bfloat16* Wt2 = (__hip_bfloat16*)carve((size_t)125 * 64 * 64 * 2);
    float* basis = (float*)carve((size_t)NE * 8 * 4);
    uint2* wi8   = (uint2*)carve((size_t)NE * 8);
    __hip_bfloat16* msg = (__hip_bfloat16*)carve((size_t)NE * 64 * 2);  // fallback path only
    int*   idx3  = (int*)carve((size_t)NF * 3 * 4);
    float* w3    = (float*)carve((size_t)NF * 3 * 4);
    // zero-initialized region: one memset covers [cellCnt | cntD | cntS | flags]
    int* zeroBase = (int*)carve((size_t)(NCELL + NF + NF + NF) * 4);
    int* cellCnt = zeroBase;
    int* cntD    = zeroBase + NCELL;
    int* cntS    = zeroBase + NCELL + NF;
    int* flags   = zeroBase + NCELL + 2*NF;
    int*   cellOffs   = (int*)carve((size_t)(NCELL+1) * 4);
    int*   cellCursor = (int*)carve((size_t)NCELL * 4);
    int*   cellId  = (int*)carve((size_t)NC * 4);
    int*   binPts  = (int*)carve((size_t)NC * 4);
    float* binPos  = (float*)carve((size_t)NC * 3 * 4);
    int*   binBatch= (int*)carve((size_t)NC * 4);
    int*   offsD   = (int*)carve((size_t)(NF+1) * 4);
    int*   cursorD = (int*)carve((size_t)NF * 4);
    int*   permD   = (int*)carve((size_t)NE * 4);
    int*   offsS   = (int*)carve((size_t)(NF+1) * 4);
    int*   cursorS = (int*)carve((size_t)NF * 4);
    int*   permS   = (int*)carve((size_t)NE * 4);

    size_t remain = (ws_size > used) ? (ws_size - used) : 0;
    const bool fullT = ((size_t)NF * TROW * 2 <= remain);
    int CH = NF;
    if (!fullT) { CH = 4096; while (CH > 512 && (size_t)CH * TROW * 2 > remain) CH >>= 1; }
    __hip_bfloat16* T = (__hip_bfloat16*)wp;
    const int NCH = NF / CH;

    hipMemsetAsync(zeroBase, 0, (size_t)(NCELL + 3*NF) * 4, stream);
    // KNN via uniform grid (exact, with brute-force fallback for flagged queries)
    bin_hist_kernel<<<NC/256, 256, 0, stream>>>(pos, cellCnt, cellId);
    bin_scan_kernel<<<1, 512, 0, stream>>>(cellCnt, cellOffs, cellCursor);
    bin_scatter_kernel<<<NC/256, 256, 0, stream>>>(pos, batch, cellId, cellCursor, binPts, binPos, binBatch);
    knn_query_kernel<<<NF/64, 256, 0, stream>>>(binPos, binPts, binBatch, cellOffs,
                                                pos_skip, batch_skip, idx3, w3, flags);
    knn_fallback_kernel<<<NF/4, 256, 0, stream>>>(pos, batch, pos_skip, batch_skip, flags, idx3, w3);
    interp_kernel<<<NF, 64, 0, stream>>>(x, x_skip, idx3, w3, X0);
    // edge prep
    basis_kernel<<<NE/256, 256, 0, stream>>>(ei, pos_skip, basis, wi8, cntD, cntS);
    scan2_kernel<<<2, 1024, 0, stream>>>(cntD, offsD, cursorD, cntS, offsS, cursorS);
    scatter2_kernel<<<dim3(NE/256, 2), 256, 0, stream>>>(ei, cursorD, permD, cursorS, permS);
    wprep_kernel<128><<<125, 256, 0, stream>>>(W0, Wt0);
    wprep_kernel<64><<<125, 256, 0, stream>>>(W1, Wt1);
    wprep_kernel<64><<<125, 256, 0, stream>>>(W2, Wt2);

    if (fullT) {
        gemm_mfma_kernel<128><<<dim3(125, NF/128), 256, 0, stream>>>(X0, Wt0, T);
        agg_fused_kernel<128><<<NF, 64, 0, stream>>>(T, basis, wi8, permD, offsD, cntD, ei, X0, root0, b0, X1);
        gemm_mfma_kernel<64><<<dim3(125, NF/128), 256, 0, stream>>>(X1, Wt1, T);
        agg_fused_kernel<64><<<NF, 64, 0, stream>>>(T, basis, wi8, permD, offsD, cntD, ei, X1, root1, b1, X2);
        gemm_mfma_kernel<64><<<dim3(125, NF/128), 256, 0, stream>>>(X2, Wt2, T);
        agg_fused_kernel<64><<<NF, 64, 0, stream>>>(T, basis, wi8, permD, offsD, cntD, ei, X2, root2, b2, (float*)d_out);
    } else {
        for (int c = 0; c < NCH; ++c) {
            gemm_mfma_kernel<128><<<dim3(125, CH/128), 256, 0, stream>>>(X0 + (size_t)c*CH*128, Wt0, T);
            msg_kernel<<<2048, 256, 0, stream>>>(T, c*CH, basis, wi8, permS, offsS, c*CH, (c+1)*CH, ei, msg);
        }
        agg_msg_kernel<128><<<NF, 64, 0, stream>>>(msg, permD, offsD, cntD, X0, root0, b0, X1);
        for (int c = 0; c < NCH; ++c) {
            gemm_mfma_kernel<64><<<dim3(125, CH/128), 256, 0, stream>>>(X1 + (size_t)c*CH*64, Wt1, T);
            msg_kernel<<<2048, 256, 0, stream>>>(T, c*CH, basis, wi8, permS, offsS, c*CH, (c+1)*CH, ei, msg);
        }
        agg_msg_kernel<64><<<NF, 64, 0, stream>>>(msg, permD, offsD, cntD, X1, root1, b1, X2);
        for (int c = 0; c < NCH; ++c) {
            gemm_mfma_kernel<64><<<dim3(125, CH/128), 256, 0, stream>>>(X2 + (size_t)c*CH*64, Wt2, T);
            msg_kernel<<<2048, 256, 0, stream>>>(T, c*CH, basis, wi8, permS, offsS, c*CH, (c+1)*CH, ei, msg);
        }
        agg_msg_kernel<64><<<NF, 64, 0, stream>>>(msg, permD, offsD, cntD, X2, root2, b2, (float*)d_out);
    }

    tail_kernel<<<(NF*3 + 255)/256, 256, 0, stream>>>(pos_skip, batch_skip, (float*)d_out);
}

// Round 6
// 713.746 us; speedup vs baseline: 1.2785x; 1.2785x over previous
//
#include <hip/hip_runtime.h>
#include <hip/hip_bf16.h>

#define NC 8192
#define NF 16384
#define NE 262144
#define TROW 8000   // 125 * 64
#define GB 8
#define NCELL 512   // GB^3
#define CELLH 0.125f
#define MAXP 1024   // max staged neighborhood points per cell block

typedef __attribute__((ext_vector_type(8))) short short8v;  // 8 bf16
typedef __attribute__((ext_vector_type(4))) float f32x4;

// ---------------- binning: histogram (points or queries) ----------------
__global__ __launch_bounds__(256) void bin_hist_kernel(
    int n, const float* __restrict__ pos, int* __restrict__ cellCnt, int* __restrict__ cellId)
{
    const int i = blockIdx.x * 256 + threadIdx.x;
    if (i >= n) return;
    const int cx = min((int)(pos[i*3+0] * GB), GB-1);
    const int cy = min((int)(pos[i*3+1] * GB), GB-1);
    const int cz = min((int)(pos[i*3+2] * GB), GB-1);
    const int cell = (cz*GB + cy)*GB + cx;
    cellId[i] = cell;
    atomicAdd(&cellCnt[cell], 1);
}

// ---------------- binning: scan 512 cells (writes sentinel) ----------------
__global__ __launch_bounds__(512) void bin_scan_kernel(
    const int* __restrict__ cellCnt, int* __restrict__ cellOffs, int* __restrict__ cellCursor)
{
    __shared__ int s[512];
    const int tid = threadIdx.x;
    const int v = cellCnt[tid];
    s[tid] = v;
    __syncthreads();
    for (int off = 1; off < 512; off <<= 1) {
        int t = (tid >= off) ? s[tid - off] : 0;
        __syncthreads();
        s[tid] += t;
        __syncthreads();
    }
    cellOffs[tid] = s[tid] - v;
    cellCursor[tid] = s[tid] - v;
    if (tid == 511) cellOffs[512] = s[511];
}

// ---------------- binning: scatter coarse points (gathered copies) ----------------
__global__ __launch_bounds__(256) void bin_scatter_kernel(
    const float* __restrict__ pos, const int* __restrict__ batch,
    const int* __restrict__ cellId, int* __restrict__ cellCursor,
    int* __restrict__ binPts, float* __restrict__ binPos, int* __restrict__ binBatch)
{
    const int i = blockIdx.x * 256 + threadIdx.x;
    const int cell = cellId[i];
    const int p = atomicAdd(&cellCursor[cell], 1);
    binPts[p] = i;
    binPos[p*3+0] = pos[i*3+0];
    binPos[p*3+1] = pos[i*3+1];
    binPos[p*3+2] = pos[i*3+2];
    binBatch[p] = batch[i];
}

// ---------------- binning: scatter query ids ----------------
__global__ __launch_bounds__(256) void qbin_scatter_kernel(
    const int* __restrict__ qCellId, int* __restrict__ qCursor, int* __restrict__ qIds)
{
    const int i = blockIdx.x * 256 + threadIdx.x;
    const int p = atomicAdd(&qCursor[qCellId[i]], 1);
    qIds[p] = i;
}

// ---------------- KNN: one block per cell, neighborhood staged in LDS ----------------
__global__ __launch_bounds__(256) void knn_cell_kernel(
    const float* __restrict__ binPos, const int* __restrict__ binBatch,
    const int* __restrict__ binPts, const int* __restrict__ cellOffs,
    const int* __restrict__ qIds, const int* __restrict__ qOffs,
    const float* __restrict__ pos_skip, const int* __restrict__ batch_skip,
    int* __restrict__ idx3, float* __restrict__ w3, int* __restrict__ flags)
{
    const int cell = blockIdx.x;
    const int cx = cell & 7, cy = (cell >> 3) & 7, cz = cell >> 6;
    const int tid = threadIdx.x;
    const int qBeg = qOffs[cell], qEnd = qOffs[cell+1];
    if (qBeg == qEnd) return;

    __shared__ float lp[MAXP*3];
    __shared__ int   lb[MAXP];
    __shared__ int   li[MAXP];
    __shared__ int   rBeg[27], rCnt[27], rDst[27];
    __shared__ int   nR_s, total_s;

    if (tid == 0) {
        int t = 0, k = 0;
        const int zlo = max(cz-1,0), zhi = min(cz+1,GB-1);
        const int ylo = max(cy-1,0), yhi = min(cy+1,GB-1);
        const int xlo = max(cx-1,0), xhi = min(cx+1,GB-1);
        for (int zz = zlo; zz <= zhi; ++zz)
        for (int yy = ylo; yy <= yhi; ++yy)
        for (int xx = xlo; xx <= xhi; ++xx) {
            const int nc = (zz*GB + yy)*GB + xx;
            const int b = cellOffs[nc], c = cellOffs[nc+1] - b;
            rBeg[k] = b; rCnt[k] = c; rDst[k] = t; t += c; ++k;
        }
        nR_s = k; total_s = t;
    }
    __syncthreads();
    const int total = total_s;
    if (total > MAXP) {          // rare adversarial density: punt to brute force
        for (int q = qBeg + tid; q < qEnd; q += 256) flags[qIds[q]] = 1;
        return;
    }
    const int nR = nR_s;
    for (int k = 0; k < nR; ++k) {
        const int b = rBeg[k], c = rCnt[k], d0 = rDst[k];
        for (int i = tid; i < c; i += 256) {
            const int p = b + i, d = d0 + i;
            lp[d*3+0] = binPos[p*3+0];
            lp[d*3+1] = binPos[p*3+1];
            lp[d*3+2] = binPos[p*3+2];
            lb[d] = binBatch[p];
            li[d] = binPts[p];
        }
    }
    __syncthreads();

    const int sub = tid & 7, g = tid >> 3;   // 32 query-groups of 8 lanes
    for (int qi = qBeg + g; qi < qEnd; qi += 32) {
        const int y = qIds[qi];
        const float px = pos_skip[y*3+0], py = pos_skip[y*3+1], pz = pos_skip[y*3+2];
        const int by = batch_skip[y];
        float b0 = INFINITY, b1 = INFINITY, b2 = INFINITY;
        int i0 = 0, i1 = 0, i2 = 0;
        auto ins = [&](float d, int gj) {
            if (d < b2) {
                if (d < b1) {
                    b2 = b1; i2 = i1;
                    if (d < b0) { b1 = b0; i1 = i0; b0 = d; i0 = gj; }
                    else        { b1 = d;  i1 = gj; }
                } else { b2 = d; i2 = gj; }
            }
        };
        for (int p = sub; p < total; p += 8) {
            const float dx = px - lp[p*3+0];
            const float dy = py - lp[p*3+1];
            const float dz = pz - lp[p*3+2];
            float d = dx*dx + dy*dy + dz*dz;
            if (lb[p] != by) d = INFINITY;
            ins(d, li[p]);
        }
        #pragma unroll
        for (int mask = 1; mask <= 4; mask <<= 1) {
            float c0 = __shfl_xor(b0, mask), c1 = __shfl_xor(b1, mask), c2 = __shfl_xor(b2, mask);
            int   j0 = __shfl_xor(i0, mask), j1 = __shfl_xor(i1, mask), j2 = __shfl_xor(i2, mask);
            ins(c0, j0); ins(c1, j1); ins(c2, j2);
        }
        if (sub == 0) {
            float rd = 1e30f;    // distance to searched-box boundary (cube faces exempt)
            if (cx > 0)    rd = fminf(rd, px - (cx-1)*CELLH);
            if (cx < GB-1) rd = fminf(rd, (cx+2)*CELLH - px);
            if (cy > 0)    rd = fminf(rd, py - (cy-1)*CELLH);
            if (cy < GB-1) rd = fminf(rd, (cy+2)*CELLH - py);
            if (cz > 0)    rd = fminf(rd, pz - (cz-1)*CELLH);
            if (cz < GB-1) rd = fminf(rd, (cz+2)*CELLH - pz);
            if (!(b2 <= rd*rd)) flags[y] = 1;   // also catches b2 == INF
            idx3[y*3+0] = i0; idx3[y*3+1] = i1; idx3[y*3+2] = i2;
            w3[y*3+0] = 1.0f / fmaxf(b0, 1e-16f);
            w3[y*3+1] = 1.0f / fmaxf(b1, 1e-16f);
            w3[y*3+2] = 1.0f / fmaxf(b2, 1e-16f);
        }
    }
}

// ---------------- KNN fallback: exact brute force for flagged queries ----------------
__global__ __launch_bounds__(256) void knn_fallback_kernel(
    const float* __restrict__ pos, const int* __restrict__ batch,
    const float* __restrict__ pos_skip, const int* __restrict__ batch_skip,
    const int* __restrict__ flags, int* __restrict__ idx3, float* __restrict__ w3)
{
    const int s = threadIdx.x & 63;
    const int y = blockIdx.x * 4 + (threadIdx.x >> 6);
    if (!flags[y]) return;   // wave-uniform
    const float px = pos_skip[y*3+0], py = pos_skip[y*3+1], pz = pos_skip[y*3+2];
    const int by = batch_skip[y];
    float b0 = INFINITY, b1 = INFINITY, b2 = INFINITY;
    int i0 = 0, i1 = 0, i2 = 0;
    auto ins = [&](float d, int gj) {
        if (d < b2) {
            if (d < b1) {
                b2 = b1; i2 = i1;
                if (d < b0) { b1 = b0; i1 = i0; b0 = d; i0 = gj; }
                else        { b1 = d;  i1 = gj; }
            } else { b2 = d; i2 = gj; }
        }
    };
    for (int j = s; j < NC; j += 64) {
        const float dx = px - pos[j*3+0];
        const float dy = py - pos[j*3+1];
        const float dz = pz - pos[j*3+2];
        float d = dx*dx + dy*dy + dz*dz;
        if (batch[j] != by) d = INFINITY;
        ins(d, j);
    }
    #pragma unroll
    for (int mask = 1; mask <= 32; mask <<= 1) {
        float c0 = __shfl_xor(b0, mask), c1 = __shfl_xor(b1, mask), c2 = __shfl_xor(b2, mask);
        int   j0 = __shfl_xor(i0, mask), j1 = __shfl_xor(i1, mask), j2 = __shfl_xor(i2, mask);
        ins(c0, j0); ins(c1, j1); ins(c2, j2);
    }
    if (s == 0) {
        idx3[y*3+0] = i0; idx3[y*3+1] = i1; idx3[y*3+2] = i2;
        w3[y*3+0] = 1.0f / fmaxf(b0, 1e-16f);
        w3[y*3+1] = 1.0f / fmaxf(b1, 1e-16f);
        w3[y*3+2] = 1.0f / fmaxf(b2, 1e-16f);
    }
}

// ---------------- interpolate + concat -> X0 [NF,128] fp32 ----------------
__global__ __launch_bounds__(64) void interp_kernel(
    const float* __restrict__ x, const float* __restrict__ x_skip,
    const int* __restrict__ idx3, const float* __restrict__ w3,
    float* __restrict__ X0)
{
    const int n = blockIdx.x, c = threadIdx.x;
    const int j0 = idx3[n*3+0], j1 = idx3[n*3+1], j2 = idx3[n*3+2];
    const float w0 = w3[n*3+0], w1 = w3[n*3+1], w2 = w3[n*3+2];
    const float inv = 1.0f / (w0 + w1 + w2);
    X0[(size_t)n*128 + c]      = (w0 * x[j0*64+c] + w1 * x[j1*64+c] + w2 * x[j2*64+c]) * inv;
    X0[(size_t)n*128 + 64 + c] = x_skip[n*64+c];
}

// ---------------- spline basis per edge + src/dst histograms ----------------
__global__ __launch_bounds__(256) void basis_kernel(
    const int* __restrict__ ei, const float* __restrict__ pos_skip,
    float* __restrict__ basis, uint2* __restrict__ wi8,
    int* __restrict__ cntD, int* __restrict__ cntS)
{
    const int e = blockIdx.x * 256 + threadIdx.x;
    const int src = ei[e], dst = ei[NE + e];
    float fr[3]; int lo[3];
    #pragma unroll
    for (int d = 0; d < 3; ++d) {
        float p = (pos_skip[dst*3+d] - pos_skip[src*3+d]) * 4.0f + 0.5f;
        p = fminf(fmaxf(p, 0.0f), 1.0f);
        float v = p * 4.0f;
        float l = fminf(floorf(v), 3.0f);
        fr[d] = v - l;
        lo[d] = (int)l;
    }
    unsigned int wlo = 0, whi = 0;
    #pragma unroll
    for (int s = 0; s < 8; ++s) {
        const int bit0 = s & 1, bit1 = (s >> 1) & 1, bit2 = (s >> 2) & 1;
        float b = (bit0 ? fr[0] : 1.0f - fr[0])
                * (bit1 ? fr[1] : 1.0f - fr[1])
                * (bit2 ? fr[2] : 1.0f - fr[2]);
        int w = (lo[0] + bit0) + 5 * (lo[1] + bit1) + 25 * (lo[2] + bit2);
        basis[(size_t)e*8 + s] = b;
        if (s < 4) wlo |= ((unsigned)w) << (8*s);
        else       whi |= ((unsigned)w) << (8*(s-4));
    }
    wi8[e] = make_uint2(wlo, whi);
    atomicAdd(&cntD[dst], 1);
    atomicAdd(&cntS[src], 1);
}

// ---------------- dual exclusive scan (block 0: D, block 1: S) ----------------
__global__ __launch_bounds__(1024) void scan2_kernel(
    const int* __restrict__ cntD, int* __restrict__ offsD, int* __restrict__ curD,
    const int* __restrict__ cntS, int* __restrict__ offsS, int* __restrict__ curS)
{
    const int* cnt = blockIdx.x ? cntS : cntD;
    int* offs   = blockIdx.x ? offsS : offsD;
    int* cursor = blockIdx.x ? curS  : curD;
    __shared__ int s[1024];
    __shared__ int carry_s;
    const int tid = threadIdx.x;
    if (tid == 0) carry_s = 0;
    __syncthreads();
    for (int ch = 0; ch < NF/1024; ++ch) {
        const int i = ch*1024 + tid;
        const int v = cnt[i];
        s[tid] = v;
        __syncthreads();
        for (int off = 1; off < 1024; off <<= 1) {
            int t = (tid >= off) ? s[tid - off] : 0;
            __syncthreads();
            s[tid] += t;
            __syncthreads();
        }
        const int incl  = s[tid];
        const int total = s[1023];
        const int base  = carry_s;
        const int excl  = base + incl - v;
        offs[i] = excl; cursor[i] = excl;
        __syncthreads();
        if (tid == 0) carry_s = base + total;
        __syncthreads();
    }
    if (tid == 0) offs[NF] = carry_s;
}

// ---------------- dual scatter: y=0 dst-sorted, y=1 src-sorted ----------------
__global__ __launch_bounds__(256) void scatter2_kernel(
    const int* __restrict__ ei, int* __restrict__ curD, int* __restrict__ permD,
    int* __restrict__ curS, int* __restrict__ permS)
{
    const int e = blockIdx.x * 256 + threadIdx.x;
    if (blockIdx.y == 0) {
        const int p = atomicAdd(&curD[ei[NE + e]], 1);
        permD[p] = e;
    } else {
        const int p = atomicAdd(&curS[ei[e]], 1);
        permS[p] = e;
    }
}

// ---------------- W prep: [125][KIN][64] fp32 -> Wt [125][64][KIN] bf16 ----------------
template<int KIN>
__global__ __launch_bounds__(256) void wprep_kernel(
    const float* __restrict__ W, __hip_bfloat16* __restrict__ Wt)
{
    __shared__ float s[KIN*64];
    const int kern = blockIdx.x;
    const float* Wk = W + (size_t)kern * KIN * 64;
    for (int i = threadIdx.x; i < KIN*64; i += 256) s[i] = Wk[i];
    __syncthreads();
    for (int i = threadIdx.x; i < 64*(KIN/8); i += 256) {
        const int o = i / (KIN/8), kb = (i % (KIN/8)) * 8;
        union { short8v v; __hip_bfloat16 h[8]; } u;
        #pragma unroll
        for (int j = 0; j < 8; ++j) u.h[j] = __float2bfloat16(s[(kb+j)*64 + o]);
        *(short8v*)&Wt[((size_t)kern*64 + o)*KIN + kb] = u.v;
    }
}

// ---------------- T = X @ W (bf16 MFMA; fp32 X staged with on-the-fly convert) ----------------
template<int KIN>
__global__ __launch_bounds__(256) void gemm_mfma_kernel(
    const float* __restrict__ X,             // [*, KIN] fp32, chunk base pre-offset
    const __hip_bfloat16* __restrict__ Wt,   // [125][64][KIN]
    __hip_bfloat16* __restrict__ T)          // [*, 8000]
{
    constexpr int BKP = KIN + 8;
    __shared__ __hip_bfloat16 As[128*BKP];
    __shared__ __hip_bfloat16 Bs[64*BKP];
    const int kern = blockIdx.x;
    const int m0   = blockIdx.y * 128;

    for (int i = threadIdx.x; i < 128*(KIN/8); i += 256) {
        const int r = i / (KIN/8), c8 = (i % (KIN/8)) * 8;
        const float* xp = &X[(size_t)(m0 + r)*KIN + c8];
        const float4 v0 = *(const float4*)xp;
        const float4 v1 = *(const float4*)(xp + 4);
        union { short8v v; __hip_bfloat16 h[8]; } u;
        u.h[0] = __float2bfloat16(v0.x); u.h[1] = __float2bfloat16(v0.y);
        u.h[2] = __float2bfloat16(v0.z); u.h[3] = __float2bfloat16(v0.w);
        u.h[4] = __float2bfloat16(v1.x); u.h[5] = __float2bfloat16(v1.y);
        u.h[6] = __float2bfloat16(v1.z); u.h[7] = __float2bfloat16(v1.w);
        *(short8v*)&As[r*BKP + c8] = u.v;
    }
    const __hip_bfloat16* Wk = Wt + (size_t)kern * 64 * KIN;
    for (int i = threadIdx.x; i < 64*(KIN/8); i += 256) {
        const int r = i / (KIN/8), c8 = (i % (KIN/8)) * 8;
        *(short8v*)&Bs[r*BKP + c8] = *(const short8v*)&Wk[(size_t)r*KIN + c8];
    }
    __syncthreads();

    const int wid  = threadIdx.x >> 6;
    const int lane = threadIdx.x & 63;
    const int lr   = lane & 15;
    const int lk   = (lane >> 4) * 8;

    f32x4 acc[2][4] = {};
    #pragma unroll
    for (int ks = 0; ks < KIN/32; ++ks) {
        short8v a0 = *(const short8v*)&As[(wid*32 +      lr)*BKP + ks*32 + lk];
        short8v a1 = *(const short8v*)&As[(wid*32 + 16 + lr)*BKP + ks*32 + lk];
        #pragma unroll
        for (int n = 0; n < 4; ++n) {
            short8v b = *(const short8v*)&Bs[(n*16 + lr)*BKP + ks*32 + lk];
            acc[0][n] = __builtin_amdgcn_mfma_f32_16x16x32_bf16(a0, b, acc[0][n], 0, 0, 0);
            acc[1][n] = __builtin_amdgcn_mfma_f32_16x16x32_bf16(a1, b, acc[1][n], 0, 0, 0);
        }
    }

    const int colBase = kern*64;
    #pragma unroll
    for (int m = 0; m < 2; ++m) {
        const int row = m0 + wid*32 + m*16 + (lane >> 4)*4;
        #pragma unroll
        for (int n = 0; n < 4; ++n) {
            const int col = colBase + n*16 + lr;
            #pragma unroll
            for (int i = 0; i < 4; ++i)
                T[(size_t)(row + i)*TROW + col] = __float2bfloat16(acc[m][n][i]);
        }
    }
}

// ---------------- FUSED (fullT path): per-dst gather from T + mean + root + ELU ----------------
template<int KIN>
__global__ __launch_bounds__(64) void agg_fused_kernel(
    const __hip_bfloat16* __restrict__ T, const float* __restrict__ basis,
    const uint2* __restrict__ wi8, const int* __restrict__ permD,
    const int* __restrict__ offsD, const int* __restrict__ cntD,
    const int* __restrict__ esrc,
    const float* __restrict__ X, const float* __restrict__ root,
    const float* __restrict__ bias, float* __restrict__ Xout)
{
    const int n = blockIdx.x, c = threadIdx.x;
    float acc = 0.0f;
    const int beg = offsD[n], num = cntD[n];
    for (int t = 0; t < num; ++t) {
        const int e = permD[beg + t];
        const int src = esrc[e];
        const uint2 w8 = wi8[e];
        const float4 bl = *(const float4*)(basis + (size_t)e*8);
        const float4 bh = *(const float4*)(basis + (size_t)e*8 + 4);
        const __hip_bfloat16* Trow = T + (size_t)src * TROW;
        acc += bl.x * __bfloat162float(Trow[((w8.x      ) & 255)*64 + c]);
        acc += bl.y * __bfloat162float(Trow[((w8.x >>  8) & 255)*64 + c]);
        acc += bl.z * __bfloat162float(Trow[((w8.x >> 16) & 255)*64 + c]);
        acc += bl.w * __bfloat162float(Trow[((w8.x >> 24) & 255)*64 + c]);
        acc += bh.x * __bfloat162float(Trow[((w8.y      ) & 255)*64 + c]);
        acc += bh.y * __bfloat162float(Trow[((w8.y >>  8) & 255)*64 + c]);
        acc += bh.z * __bfloat162float(Trow[((w8.y >> 16) & 255)*64 + c]);
        acc += bh.w * __bfloat162float(Trow[((w8.y >> 24) & 255)*64 + c]);
    }
    const float agg = acc / fmaxf((float)num, 1.0f);
    const float* xr = X + (size_t)n * KIN;
    float r = 0.0f;
    #pragma unroll 16
    for (int i = 0; i < KIN; ++i) r = fmaf(xr[i], root[i*64 + c], r);
    float o = agg + r + bias[c];
    o = (o > 0.0f) ? o : expm1f(o);
    Xout[(size_t)n*64 + c] = o;
}

// ---------------- chunked path: per-edge msg for edges with src in chunk ----------------
__global__ __launch_bounds__(256) void msg_kernel(
    const __hip_bfloat16* __restrict__ Tc, int n0,
    const float* __restrict__ basis, const uint2* __restrict__ wi8,
    const int* __restrict__ permS, const int* __restrict__ offsS,
    int c0, int c1, const int* __restrict__ esrc,
    __hip_bfloat16* __restrict__ msg)
{
    const int eBeg = offsS[c0];
    const int eEnd = offsS[c1];
    const int lane = threadIdx.x & 63;
    const int sub  = threadIdx.x >> 6;
    for (int p = eBeg + blockIdx.x*4 + sub; p < eEnd; p += gridDim.x*4) {
        const int e = permS[p];
        const int src = esrc[e];
        const uint2 w8 = wi8[e];
        const float* bs = basis + (size_t)e*8;
        const __hip_bfloat16* Trow = Tc + (size_t)(src - n0) * TROW;
        float acc = 0.0f;
        #pragma unroll
        for (int s = 0; s < 4; ++s) {
            const int wk = (w8.x >> (8*s)) & 255;
            acc += bs[s] * __bfloat162float(Trow[wk*64 + lane]);
        }
        #pragma unroll
        for (int s = 0; s < 4; ++s) {
            const int wk = (w8.y >> (8*s)) & 255;
            acc += bs[4+s] * __bfloat162float(Trow[wk*64 + lane]);
        }
        msg[(size_t)e*64 + lane] = __float2bfloat16(acc);
    }
}

template<int KIN>
__global__ __launch_bounds__(64) void agg_msg_kernel(
    const __hip_bfloat16* __restrict__ msg, const int* __restrict__ permD,
    const int* __restrict__ offsD, const int* __restrict__ cntD,
    const float* __restrict__ X, const float* __restrict__ root,
    const float* __restrict__ bias, float* __restrict__ Xout)
{
    const int n = blockIdx.x, c = threadIdx.x;
    float acc = 0.0f;
    const int beg = offsD[n], num = cntD[n];
    for (int t = 0; t < num; ++t) {
        const int e = permD[beg + t];
        acc += __bfloat162float(msg[(size_t)e*64 + c]);
    }
    const float agg = acc / fmaxf((float)num, 1.0f);
    const float* xr = X + (size_t)n * KIN;
    float r = 0.0f;
    #pragma unroll 16
    for (int i = 0; i < KIN; ++i) r = fmaf(xr[i], root[i*64 + c], r);
    float o = agg + r + bias[c];
    o = (o > 0.0f) ? o : expm1f(o);
    Xout[(size_t)n*64 + c] = o;
}

// ---------------- tail: pos_skip + batch_skip passthrough ----------------
__global__ __launch_bounds__(256) void tail_kernel(
    const float* __restrict__ pos_skip, const int* __restrict__ batch_skip,
    float* __restrict__ out)
{
    const int i = blockIdx.x * 256 + threadIdx.x;
    if (i < NF*3) out[1048576 + i] = pos_skip[i];
    if (i < NF)   ((int*)out)[1048576 + NF*3 + i] = batch_skip[i];
}

extern "C" void kernel_launch(void* const* d_in, const int* in_sizes, int n_in,
                              void* d_out, int out_size, void* d_ws, size_t ws_size,
                              hipStream_t stream)
{
    const float* x          = (const float*)d_in[0];
    const float* pos        = (const float*)d_in[1];
    const int*   batch      = (const int*)d_in[2];
    const float* x_skip     = (const float*)d_in[3];
    const float* pos_skip   = (const float*)d_in[4];
    const int*   batch_skip = (const int*)d_in[5];
    const int*   ei         = (const int*)d_in[6];
    const float* W0    = (const float*)d_in[7];
    const float* root0 = (const float*)d_in[8];
    const float* b0    = (const float*)d_in[9];
    const float* W1    = (const float*)d_in[10];
    const float* root1 = (const float*)d_in[11];
    const float* b1    = (const float*)d_in[12];
    const float* W2    = (const float*)d_in[13];
    const float* root2 = (const float*)d_in[14];
    const float* b2    = (const float*)d_in[15];

    char* wp = (char*)d_ws;
    size_t used = 0;
    auto carve = [&](size_t bytes) {
        char* p = wp;
        size_t a = (bytes + 255) & ~(size_t)255;
        wp += a; used += a;
        return p;
    };
    float* X0    = (float*)carve((size_t)NF * 128 * 4);
    float* X1    = (float*)carve((size_t)NF * 64 * 4);
    float* X2    = (float*)carve((size_t)NF * 64 * 4);
    __hip_bfloat16* Wt0 = (__hip_bfloat16*)carve((size_t)125 * 128 * 64 * 2);
    __hip_bfloat16* Wt1 = (__hip_bfloat16*)carve((size_t)125 * 64 * 64 * 2);
    __hip_bfloat16* Wt2 = (__hip_bfloat16*)carve((size_t)125 * 64 * 64 * 2);
    float* basis = (float*)carve((size_t)NE * 8 * 4);
    uint2* wi8   = (uint2*)carve((size_t)NE * 8);
    __hip_bfloat16* msg = (__hip_bfloat16*)carve((size_t)NE * 64 * 2);  // chunked path only
    int*   idx3  = (int*)carve((size_t)NF * 3 * 4);
    float* w3    = (float*)carve((size_t)NF * 3 * 4);
    // zero-initialized region: one memset covers [cellCnt | qCellCnt | cntD | cntS | flags]
    int* zeroBase = (int*)carve((size_t)(2*NCELL + 3*NF) * 4);
    int* cellCnt  = zeroBase;
    int* qCellCnt = zeroBase + NCELL;
    int* cntD     = zeroBase + 2*NCELL;
    int* cntS     = zeroBase + 2*NCELL + NF;
    int* flags    = zeroBase + 2*NCELL + 2*NF;
    int*   cellOffs   = (int*)carve((size_t)(NCELL+1) * 4);
    int*   cellCursor = (int*)carve((size_t)NCELL * 4);
    int*   qOffs      = (int*)carve((size_t)(NCELL+1) * 4);
    int*   qCursor    = (int*)carve((size_t)NCELL * 4);
    int*   cellId  = (int*)carve((size_t)NC * 4);
    int*   qCellId = (int*)carve((size_t)NF * 4);
    int*   qIds    = (int*)carve((size_t)NF * 4);
    int*   binPts  = (int*)carve((size_t)NC * 4);
    float* binPos  = (float*)carve((size_t)NC * 3 * 4);
    int*   binBatch= (int*)carve((size_t)NC * 4);
    int*   offsD   = (int*)carve((size_t)(NF+1) * 4);
    int*   cursorD = (int*)carve((size_t)NF * 4);
    int*   permD   = (int*)carve((size_t)NE * 4);
    int*   offsS   = (int*)carve((size_t)(NF+1) * 4);
    int*   cursorS = (int*)carve((size_t)NF * 4);
    int*   permS   = (int*)carve((size_t)NE * 4);

    size_t remain = (ws_size > used) ? (ws_size - used) : 0;
    int CH = NF;
    while (CH > 512 && (size_t)CH * TROW * 2 > remain) CH >>= 1;   // adaptive (R3 behavior)
    const bool fullT = (CH == NF);
    __hip_bfloat16* T = (__hip_bfloat16*)wp;
    const int NCH = NF / CH;

    hipMemsetAsync(zeroBase, 0, (size_t)(2*NCELL + 3*NF) * 4, stream);
    // KNN via uniform grid, cell-centric (exact; brute-force fallback for flagged)
    bin_hist_kernel<<<NC/256, 256, 0, stream>>>(NC, pos, cellCnt, cellId);
    bin_hist_kernel<<<NF/256, 256, 0, stream>>>(NF, pos_skip, qCellCnt, qCellId);
    bin_scan_kernel<<<1, 512, 0, stream>>>(cellCnt, cellOffs, cellCursor);
    bin_scan_kernel<<<1, 512, 0, stream>>>(qCellCnt, qOffs, qCursor);
    bin_scatter_kernel<<<NC/256, 256, 0, stream>>>(pos, batch, cellId, cellCursor, binPts, binPos, binBatch);
    qbin_scatter_kernel<<<NF/256, 256, 0, stream>>>(qCellId, qCursor, qIds);
    knn_cell_kernel<<<NCELL, 256, 0, stream>>>(binPos, binBatch, binPts, cellOffs,
                                               qIds, qOffs, pos_skip, batch_skip, idx3, w3, flags);
    knn_fallback_kernel<<<NF/4, 256, 0, stream>>>(pos, batch, pos_skip, batch_skip, flags, idx3, w3);
    interp_kernel<<<NF, 64, 0, stream>>>(x, x_skip, idx3, w3, X0);
    // edge prep
    basis_kernel<<<NE/256, 256, 0, stream>>>(ei, pos_skip, basis, wi8, cntD, cntS);
    scan2_kernel<<<2, 1024, 0, stream>>>(cntD, offsD, cursorD, cntS, offsS, cursorS);
    scatter2_kernel<<<dim3(NE/256, 2), 256, 0, stream>>>(ei, cursorD, permD, cursorS, permS);
    wprep_kernel<128><<<125, 256, 0, stream>>>(W0, Wt0);
    wprep_kernel<64><<<125, 256, 0, stream>>>(W1, Wt1);
    wprep_kernel<64><<<125, 256, 0, stream>>>(W2, Wt2);

    if (fullT) {
        gemm_mfma_kernel<128><<<dim3(125, NF/128), 256, 0, stream>>>(X0, Wt0, T);
        agg_fused_kernel<128><<<NF, 64, 0, stream>>>(T, basis, wi8, permD, offsD, cntD, ei, X0, root0, b0, X1);
        gemm_mfma_kernel<64><<<dim3(125, NF/128), 256, 0, stream>>>(X1, Wt1, T);
        agg_fused_kernel<64><<<NF, 64, 0, stream>>>(T, basis, wi8, permD, offsD, cntD, ei, X1, root1, b1, X2);
        gemm_mfma_kernel<64><<<dim3(125, NF/128), 256, 0, stream>>>(X2, Wt2, T);
        agg_fused_kernel<64><<<NF, 64, 0, stream>>>(T, basis, wi8, permD, offsD, cntD, ei, X2, root2, b2, (float*)d_out);
    } else {
        for (int c = 0; c < NCH; ++c) {
            gemm_mfma_kernel<128><<<dim3(125, CH/128), 256, 0, stream>>>(X0 + (size_t)c*CH*128, Wt0, T);
            msg_kernel<<<2048, 256, 0, stream>>>(T, c*CH, basis, wi8, permS, offsS, c*CH, (c+1)*CH, ei, msg);
        }
        agg_msg_kernel<128><<<NF, 64, 0, stream>>>(msg, permD, offsD, cntD, X0, root0, b0, X1);
        for (int c = 0; c < NCH; ++c) {
            gemm_mfma_kernel<64><<<dim3(125, CH/128), 256, 0, stream>>>(X1 + (size_t)c*CH*64, Wt1, T);
            msg_kernel<<<2048, 256, 0, stream>>>(T, c*CH, basis, wi8, permS, offsS, c*CH, (c+1)*CH, ei, msg);
        }
        agg_msg_kernel<64><<<NF, 64, 0, stream>>>(msg, permD, offsD, cntD, X1, root1, b1, X2);
        for (int c = 0; c < NCH; ++c) {
            gemm_mfma_kernel<64><<<dim3(125, CH/128), 256, 0, stream>>>(X2 + (size_t)c*CH*64, Wt2, T);
            msg_kernel<<<2048, 256, 0, stream>>>(T, c*CH, basis, wi8, permS, offsS, c*CH, (c+1)*CH, ei, msg);
        }
        agg_msg_kernel<64><<<NF, 64, 0, stream>>>(msg, permD, offsD, cntD, X2, root2, b2, (float*)d_out);
    }

    tail_kernel<<<(NF*3 + 255)/256, 256, 0, stream>>>(pos_skip, batch_skip, (float*)d_out);
}

// Round 8
// 651.181 us; speedup vs baseline: 1.4014x; 1.0961x over previous
//
#include <hip/hip_runtime.h>
#include <hip/hip_bf16.h>

#define NC 8192
#define NF 16384
#define NE 262144
#define TROW 8000   // 125 * 64
#define GB 8
#define NCELL 512   // GB^3
#define CELLH 0.125f
#define MAXP 1024

typedef __attribute__((ext_vector_type(8))) short short8v;  // 8 bf16
typedef __attribute__((ext_vector_type(4))) float f32x4;

// ---------------- binning: histograms for points (y=0) and queries (y=1) ----------------
__global__ __launch_bounds__(256) void hist2_kernel(
    const float* __restrict__ pos, const float* __restrict__ pos_skip,
    int* __restrict__ cellCnt, int* __restrict__ cellId,
    int* __restrict__ qCellCnt, int* __restrict__ qCellId)
{
    const int i = blockIdx.x * 256 + threadIdx.x;
    if (blockIdx.y == 0) {
        if (i >= NC) return;
        const int cx = min((int)(pos[i*3+0] * GB), GB-1);
        const int cy = min((int)(pos[i*3+1] * GB), GB-1);
        const int cz = min((int)(pos[i*3+2] * GB), GB-1);
        const int cell = (cz*GB + cy)*GB + cx;
        cellId[i] = cell;
        atomicAdd(&cellCnt[cell], 1);
    } else {
        const int cx = min((int)(pos_skip[i*3+0] * GB), GB-1);
        const int cy = min((int)(pos_skip[i*3+1] * GB), GB-1);
        const int cz = min((int)(pos_skip[i*3+2] * GB), GB-1);
        const int cell = (cz*GB + cy)*GB + cx;
        qCellId[i] = cell;
        atomicAdd(&qCellCnt[cell], 1);
    }
}

// ---------------- binning: scan 512 cells x2 (block 0: points, block 1: queries) ----------------
__global__ __launch_bounds__(512) void cellscan2_kernel(
    const int* __restrict__ cellCnt, int* __restrict__ cellOffs, int* __restrict__ cellCursor,
    const int* __restrict__ qCellCnt, int* __restrict__ qOffs, int* __restrict__ qCursor)
{
    const int* cnt = blockIdx.x ? qCellCnt : cellCnt;
    int* offs   = blockIdx.x ? qOffs   : cellOffs;
    int* cursor = blockIdx.x ? qCursor : cellCursor;
    __shared__ int s[512];
    const int tid = threadIdx.x;
    const int v = cnt[tid];
    s[tid] = v;
    __syncthreads();
    for (int off = 1; off < 512; off <<= 1) {
        int t = (tid >= off) ? s[tid - off] : 0;
        __syncthreads();
        s[tid] += t;
        __syncthreads();
    }
    offs[tid] = s[tid] - v;
    cursor[tid] = s[tid] - v;
    if (tid == 511) offs[512] = s[511];
}

// ---------------- binning: scatter points (y=0) and query ids (y=1) ----------------
__global__ __launch_bounds__(256) void binscat2_kernel(
    const float* __restrict__ pos, const int* __restrict__ batch,
    const int* __restrict__ cellId, int* __restrict__ cellCursor,
    int* __restrict__ binPts, float* __restrict__ binPos, int* __restrict__ binBatch,
    const int* __restrict__ qCellId, int* __restrict__ qCursor, int* __restrict__ qIds)
{
    const int i = blockIdx.x * 256 + threadIdx.x;
    if (blockIdx.y == 0) {
        if (i >= NC) return;
        const int cell = cellId[i];
        const int p = atomicAdd(&cellCursor[cell], 1);
        binPts[p] = i;
        binPos[p*3+0] = pos[i*3+0];
        binPos[p*3+1] = pos[i*3+1];
        binPos[p*3+2] = pos[i*3+2];
        binBatch[p] = batch[i];
    } else {
        const int p = atomicAdd(&qCursor[qCellId[i]], 1);
        qIds[p] = i;
    }
}

// ---------------- KNN: one block per cell, neighborhood staged in LDS ----------------
__global__ __launch_bounds__(256) void knn_cell_kernel(
    const float* __restrict__ binPos, const int* __restrict__ binBatch,
    const int* __restrict__ binPts, const int* __restrict__ cellOffs,
    const int* __restrict__ qIds, const int* __restrict__ qOffs,
    const float* __restrict__ pos_skip, const int* __restrict__ batch_skip,
    int* __restrict__ idx3, float* __restrict__ w3, int* __restrict__ flags)
{
    const int cell = blockIdx.x;
    const int cx = cell & 7, cy = (cell >> 3) & 7, cz = cell >> 6;
    const int tid = threadIdx.x;
    const int qBeg = qOffs[cell], qEnd = qOffs[cell+1];
    if (qBeg == qEnd) return;

    __shared__ float lp[MAXP*3];
    __shared__ int   lb[MAXP];
    __shared__ int   li[MAXP];
    __shared__ int   rBeg[27], rCnt[27], rDst[27];
    __shared__ int   nR_s, total_s;

    if (tid == 0) {
        int t = 0, k = 0;
        const int zlo = max(cz-1,0), zhi = min(cz+1,GB-1);
        const int ylo = max(cy-1,0), yhi = min(cy+1,GB-1);
        const int xlo = max(cx-1,0), xhi = min(cx+1,GB-1);
        for (int zz = zlo; zz <= zhi; ++zz)
        for (int yy = ylo; yy <= yhi; ++yy)
        for (int xx = xlo; xx <= xhi; ++xx) {
            const int nc = (zz*GB + yy)*GB + xx;
            const int b = cellOffs[nc], c = cellOffs[nc+1] - b;
            rBeg[k] = b; rCnt[k] = c; rDst[k] = t; t += c; ++k;
        }
        nR_s = k; total_s = t;
    }
    __syncthreads();
    const int total = total_s;
    if (total > MAXP) {
        for (int q = qBeg + tid; q < qEnd; q += 256) flags[qIds[q]] = 1;
        return;
    }
    const int nR = nR_s;
    for (int k = 0; k < nR; ++k) {
        const int b = rBeg[k], c = rCnt[k], d0 = rDst[k];
        for (int i = tid; i < c; i += 256) {
            const int p = b + i, d = d0 + i;
            lp[d*3+0] = binPos[p*3+0];
            lp[d*3+1] = binPos[p*3+1];
            lp[d*3+2] = binPos[p*3+2];
            lb[d] = binBatch[p];
            li[d] = binPts[p];
        }
    }
    __syncthreads();

    const int sub = tid & 7, g = tid >> 3;
    for (int qi = qBeg + g; qi < qEnd; qi += 32) {
        const int y = qIds[qi];
        const float px = pos_skip[y*3+0], py = pos_skip[y*3+1], pz = pos_skip[y*3+2];
        const int by = batch_skip[y];
        float b0 = INFINITY, b1 = INFINITY, b2 = INFINITY;
        int i0 = 0, i1 = 0, i2 = 0;
        auto ins = [&](float d, int gj) {
            if (d < b2) {
                if (d < b1) {
                    b2 = b1; i2 = i1;
                    if (d < b0) { b1 = b0; i1 = i0; b0 = d; i0 = gj; }
                    else        { b1 = d;  i1 = gj; }
                } else { b2 = d; i2 = gj; }
            }
        };
        for (int p = sub; p < total; p += 8) {
            const float dx = px - lp[p*3+0];
            const float dy = py - lp[p*3+1];
            const float dz = pz - lp[p*3+2];
            float d = dx*dx + dy*dy + dz*dz;
            if (lb[p] != by) d = INFINITY;
            ins(d, li[p]);
        }
        #pragma unroll
        for (int mask = 1; mask <= 4; mask <<= 1) {
            float c0 = __shfl_xor(b0, mask), c1 = __shfl_xor(b1, mask), c2 = __shfl_xor(b2, mask);
            int   j0 = __shfl_xor(i0, mask), j1 = __shfl_xor(i1, mask), j2 = __shfl_xor(i2, mask);
            ins(c0, j0); ins(c1, j1); ins(c2, j2);
        }
        if (sub == 0) {
            float rd = 1e30f;
            if (cx > 0)    rd = fminf(rd, px - (cx-1)*CELLH);
            if (cx < GB-1) rd = fminf(rd, (cx+2)*CELLH - px);
            if (cy > 0)    rd = fminf(rd, py - (cy-1)*CELLH);
            if (cy < GB-1) rd = fminf(rd, (cy+2)*CELLH - py);
            if (cz > 0)    rd = fminf(rd, pz - (cz-1)*CELLH);
            if (cz < GB-1) rd = fminf(rd, (cz+2)*CELLH - pz);
            if (!(b2 <= rd*rd)) flags[y] = 1;
            idx3[y*3+0] = i0; idx3[y*3+1] = i1; idx3[y*3+2] = i2;
            w3[y*3+0] = 1.0f / fmaxf(b0, 1e-16f);
            w3[y*3+1] = 1.0f / fmaxf(b1, 1e-16f);
            w3[y*3+2] = 1.0f / fmaxf(b2, 1e-16f);
        }
    }
}

// ---------------- KNN fallback: exact brute force for flagged queries ----------------
__global__ __launch_bounds__(256) void knn_fallback_kernel(
    const float* __restrict__ pos, const int* __restrict__ batch,
    const float* __restrict__ pos_skip, const int* __restrict__ batch_skip,
    const int* __restrict__ flags, int* __restrict__ idx3, float* __restrict__ w3)
{
    const int s = threadIdx.x & 63;
    const int y = blockIdx.x * 4 + (threadIdx.x >> 6);
    if (!flags[y]) return;
    const float px = pos_skip[y*3+0], py = pos_skip[y*3+1], pz = pos_skip[y*3+2];
    const int by = batch_skip[y];
    float b0 = INFINITY, b1 = INFINITY, b2 = INFINITY;
    int i0 = 0, i1 = 0, i2 = 0;
    auto ins = [&](float d, int gj) {
        if (d < b2) {
            if (d < b1) {
                b2 = b1; i2 = i1;
                if (d < b0) { b1 = b0; i1 = i0; b0 = d; i0 = gj; }
                else        { b1 = d;  i1 = gj; }
            } else { b2 = d; i2 = gj; }
        }
    };
    for (int j = s; j < NC; j += 64) {
        const float dx = px - pos[j*3+0];
        const float dy = py - pos[j*3+1];
        const float dz = pz - pos[j*3+2];
        float d = dx*dx + dy*dy + dz*dz;
        if (batch[j] != by) d = INFINITY;
        ins(d, j);
    }
    #pragma unroll
    for (int mask = 1; mask <= 32; mask <<= 1) {
        float c0 = __shfl_xor(b0, mask), c1 = __shfl_xor(b1, mask), c2 = __shfl_xor(b2, mask);
        int   j0 = __shfl_xor(i0, mask), j1 = __shfl_xor(i1, mask), j2 = __shfl_xor(i2, mask);
        ins(c0, j0); ins(c1, j1); ins(c2, j2);
    }
    if (s == 0) {
        idx3[y*3+0] = i0; idx3[y*3+1] = i1; idx3[y*3+2] = i2;
        w3[y*3+0] = 1.0f / fmaxf(b0, 1e-16f);
        w3[y*3+1] = 1.0f / fmaxf(b1, 1e-16f);
        w3[y*3+2] = 1.0f / fmaxf(b2, 1e-16f);
    }
}

// ---------------- interpolate + concat -> X0 fp32 + Xb0 bf16 ----------------
__global__ __launch_bounds__(64) void interp_kernel(
    const float* __restrict__ x, const float* __restrict__ x_skip,
    const int* __restrict__ idx3, const float* __restrict__ w3,
    float* __restrict__ X0, __hip_bfloat16* __restrict__ Xb0)
{
    const int n = blockIdx.x, c = threadIdx.x;
    const int j0 = idx3[n*3+0], j1 = idx3[n*3+1], j2 = idx3[n*3+2];
    const float w0 = w3[n*3+0], w1 = w3[n*3+1], w2 = w3[n*3+2];
    const float inv = 1.0f / (w0 + w1 + w2);
    const float h = (w0 * x[j0*64+c] + w1 * x[j1*64+c] + w2 * x[j2*64+c]) * inv;
    const float xs = x_skip[n*64+c];
    X0[(size_t)n*128 + c]      = h;
    X0[(size_t)n*128 + 64 + c] = xs;
    Xb0[(size_t)n*128 + c]      = __float2bfloat16(h);
    Xb0[(size_t)n*128 + 64 + c] = __float2bfloat16(xs);
}

// ---------------- spline basis per edge + src/dst histograms ----------------
__global__ __launch_bounds__(256) void basis_kernel(
    const int* __restrict__ ei, const float* __restrict__ pos_skip,
    float* __restrict__ basis, uint2* __restrict__ wi8,
    int* __restrict__ cntD, int* __restrict__ cntS)
{
    const int e = blockIdx.x * 256 + threadIdx.x;
    const int src = ei[e], dst = ei[NE + e];
    float fr[3]; int lo[3];
    #pragma unroll
    for (int d = 0; d < 3; ++d) {
        float p = (pos_skip[dst*3+d] - pos_skip[src*3+d]) * 4.0f + 0.5f;
        p = fminf(fmaxf(p, 0.0f), 1.0f);
        float v = p * 4.0f;
        float l = fminf(floorf(v), 3.0f);
        fr[d] = v - l;
        lo[d] = (int)l;
    }
    unsigned int wlo = 0, whi = 0;
    #pragma unroll
    for (int s = 0; s < 8; ++s) {
        const int bit0 = s & 1, bit1 = (s >> 1) & 1, bit2 = (s >> 2) & 1;
        float b = (bit0 ? fr[0] : 1.0f - fr[0])
                * (bit1 ? fr[1] : 1.0f - fr[1])
                * (bit2 ? fr[2] : 1.0f - fr[2]);
        int w = (lo[0] + bit0) + 5 * (lo[1] + bit1) + 25 * (lo[2] + bit2);
        basis[(size_t)e*8 + s] = b;
        if (s < 4) wlo |= ((unsigned)w) << (8*s);
        else       whi |= ((unsigned)w) << (8*(s-4));
    }
    wi8[e] = make_uint2(wlo, whi);
    atomicAdd(&cntD[dst], 1);
    atomicAdd(&cntS[src], 1);
}

// ---------------- dual exclusive scan over NF counts ----------------
__global__ __launch_bounds__(1024) void scan2_kernel(
    const int* __restrict__ cntD, int* __restrict__ offsD, int* __restrict__ curD,
    const int* __restrict__ cntS, int* __restrict__ offsS, int* __restrict__ curS)
{
    const int* cnt = blockIdx.x ? cntS : cntD;
    int* offs   = blockIdx.x ? offsS : offsD;
    int* cursor = blockIdx.x ? curS  : curD;
    __shared__ int s[1024];
    __shared__ int carry_s;
    const int tid = threadIdx.x;
    if (tid == 0) carry_s = 0;
    __syncthreads();
    for (int ch = 0; ch < NF/1024; ++ch) {
        const int i = ch*1024 + tid;
        const int v = cnt[i];
        s[tid] = v;
        __syncthreads();
        for (int off = 1; off < 1024; off <<= 1) {
            int t = (tid >= off) ? s[tid - off] : 0;
            __syncthreads();
            s[tid] += t;
            __syncthreads();
        }
        const int incl  = s[tid];
        const int total = s[1023];
        const int base  = carry_s;
        const int excl  = base + incl - v;
        offs[i] = excl; cursor[i] = excl;
        __syncthreads();
        if (tid == 0) carry_s = base + total;
        __syncthreads();
    }
    if (tid == 0) offs[NF] = carry_s;
}

// ---------------- dual scatter: y=0 dst-sorted, y=1 src-sorted ----------------
__global__ __launch_bounds__(256) void scatter2_kernel(
    const int* __restrict__ ei, int* __restrict__ curD, int* __restrict__ permD,
    int* __restrict__ curS, int* __restrict__ permS)
{
    const int e = blockIdx.x * 256 + threadIdx.x;
    if (blockIdx.y == 0) {
        const int p = atomicAdd(&curD[ei[NE + e]], 1);
        permD[p] = e;
    } else {
        const int p = atomicAdd(&curS[ei[e]], 1);
        permS[p] = e;
    }
}

// ---------------- W prep, all 3 layers: [125][KIN][64] fp32 -> [125][64][KIN] bf16 ----------------
__global__ __launch_bounds__(256) void wprep_all_kernel(
    const float* __restrict__ W0, const float* __restrict__ W1, const float* __restrict__ W2,
    __hip_bfloat16* __restrict__ Wt0, __hip_bfloat16* __restrict__ Wt1, __hip_bfloat16* __restrict__ Wt2)
{
    const int which = blockIdx.y;
    const float* W = (which == 0) ? W0 : (which == 1 ? W1 : W2);
    __hip_bfloat16* Wt = (which == 0) ? Wt0 : (which == 1 ? Wt1 : Wt2);
    const int KIN = (which == 0) ? 128 : 64;
    __shared__ float s[128*64];
    const int kern = blockIdx.x;
    const float* Wk = W + (size_t)kern * KIN * 64;
    for (int i = threadIdx.x; i < KIN*64; i += 256) s[i] = Wk[i];
    __syncthreads();
    const int nk8 = KIN/8;
    for (int i = threadIdx.x; i < 64*nk8; i += 256) {
        const int o = i / nk8, kb = (i % nk8) * 8;
        union { short8v v; __hip_bfloat16 h[8]; } u;
        #pragma unroll
        for (int j = 0; j < 8; ++j) u.h[j] = __float2bfloat16(s[(kb+j)*64 + o]);
        *(short8v*)&Wt[((size_t)kern*64 + o)*KIN + kb] = u.v;
    }
}

// ---------------- T = Xb @ W (bf16 MFMA, coalesced epilogue via LDS transpose) ----------------
template<int KIN>
__global__ __launch_bounds__(256) void gemm_mfma_kernel(
    const __hip_bfloat16* __restrict__ Xb,   // [*, KIN] bf16, chunk base pre-offset
    const __hip_bfloat16* __restrict__ Wt,   // [125][64][KIN]
    __hip_bfloat16* __restrict__ T)          // [*, 8000]
{
    constexpr int BKP = KIN + 8;
    __shared__ __hip_bfloat16 As[128*BKP];   // also reused as C-tile [128][72]
    __shared__ __hip_bfloat16 Bs[64*BKP];
    const int kern = blockIdx.x;
    const int m0   = blockIdx.y * 128;

    for (int i = threadIdx.x; i < 128*(KIN/8); i += 256) {
        const int r = i / (KIN/8), c8 = (i % (KIN/8)) * 8;
        *(short8v*)&As[r*BKP + c8] = *(const short8v*)&Xb[(size_t)(m0 + r)*KIN + c8];
    }
    const __hip_bfloat16* Wk = Wt + (size_t)kern * 64 * KIN;
    for (int i = threadIdx.x; i < 64*(KIN/8); i += 256) {
        const int r = i / (KIN/8), c8 = (i % (KIN/8)) * 8;
        *(short8v*)&Bs[r*BKP + c8] = *(const short8v*)&Wk[(size_t)r*KIN + c8];
    }
    __syncthreads();

    const int wid  = threadIdx.x >> 6;
    const int lane = threadIdx.x & 63;
    const int lr   = lane & 15;
    const int lk   = (lane >> 4) * 8;

    f32x4 acc[2][4] = {};
    #pragma unroll
    for (int ks = 0; ks < KIN/32; ++ks) {
        short8v a0 = *(const short8v*)&As[(wid*32 +      lr)*BKP + ks*32 + lk];
        short8v a1 = *(const short8v*)&As[(wid*32 + 16 + lr)*BKP + ks*32 + lk];
        #pragma unroll
        for (int n = 0; n < 4; ++n) {
            short8v b = *(const short8v*)&Bs[(n*16 + lr)*BKP + ks*32 + lk];
            acc[0][n] = __builtin_amdgcn_mfma_f32_16x16x32_bf16(a0, b, acc[0][n], 0, 0, 0);
            acc[1][n] = __builtin_amdgcn_mfma_f32_16x16x32_bf16(a1, b, acc[1][n], 0, 0, 0);
        }
    }

    // epilogue: acc -> LDS C-tile [128][72] (pad keeps banks <=2-way, 144B stride is 16B-aligned)
    __syncthreads();
    __hip_bfloat16* Ct = As;
    #pragma unroll
    for (int m = 0; m < 2; ++m) {
        const int rowL = wid*32 + m*16 + (lane >> 4)*4;
        #pragma unroll
        for (int n = 0; n < 4; ++n) {
            const int colL = n*16 + lr;
            #pragma unroll
            for (int i = 0; i < 4; ++i)
                Ct[(rowL + i)*72 + colL] = __float2bfloat16(acc[m][n][i]);
        }
    }
    __syncthreads();
    // coalesced store: 128 rows x 8 chunks of 8 bf16 = 1024 short8v stores
    const size_t tbase = (size_t)m0 * TROW + kern*64;
    #pragma unroll
    for (int u = threadIdx.x; u < 1024; u += 256) {
        const int row = u >> 3, ch = (u & 7) * 8;
        *(short8v*)&T[tbase + (size_t)row*TROW + ch] = *(short8v*)&Ct[row*72 + ch];
    }
}

// ---------------- FUSED: per-dst gather from T + mean + root + bias + ELU (+tail) ----------------
template<int KIN>
__global__ __launch_bounds__(64) void agg_fused_kernel(
    const __hip_bfloat16* __restrict__ T, const float* __restrict__ basis,
    const uint2* __restrict__ wi8, const int* __restrict__ permD,
    const int* __restrict__ offsD, const int* __restrict__ cntD,
    const int* __restrict__ esrc,
    const float* __restrict__ X, const float* __restrict__ root,
    const float* __restrict__ bias, float* __restrict__ Xout,
    __hip_bfloat16* __restrict__ Xbout,
    const float* __restrict__ tpos, const int* __restrict__ tbatch)
{
    const int n = blockIdx.x, c = threadIdx.x;
    float acc = 0.0f;
    const int beg = offsD[n], num = cntD[n];
    for (int t = 0; t < num; ++t) {
        const int e = permD[beg + t];
        const int src = esrc[e];
        const uint2 w8 = wi8[e];
        const float4 bl = *(const float4*)(basis + (size_t)e*8);
        const float4 bh = *(const float4*)(basis + (size_t)e*8 + 4);
        const __hip_bfloat16* Trow = T + (size_t)src * TROW;
        acc += bl.x * __bfloat162float(Trow[((w8.x      ) & 255)*64 + c]);
        acc += bl.y * __bfloat162float(Trow[((w8.x >>  8) & 255)*64 + c]);
        acc += bl.z * __bfloat162float(Trow[((w8.x >> 16) & 255)*64 + c]);
        acc += bl.w * __bfloat162float(Trow[((w8.x >> 24) & 255)*64 + c]);
        acc += bh.x * __bfloat162float(Trow[((w8.y      ) & 255)*64 + c]);
        acc += bh.y * __bfloat162float(Trow[((w8.y >>  8) & 255)*64 + c]);
        acc += bh.z * __bfloat162float(Trow[((w8.y >> 16) & 255)*64 + c]);
        acc += bh.w * __bfloat162float(Trow[((w8.y >> 24) & 255)*64 + c]);
    }
    const float agg = acc / fmaxf((float)num, 1.0f);
    const float* xr = X + (size_t)n * KIN;
    float r = 0.0f;
    #pragma unroll 16
    for (int i = 0; i < KIN; ++i) r = fmaf(xr[i], root[i*64 + c], r);
    float o = agg + r + bias[c];
    o = (o > 0.0f) ? o : expm1f(o);
    Xout[(size_t)n*64 + c] = o;
    if (Xbout) Xbout[(size_t)n*64 + c] = __float2bfloat16(o);
    if (tpos) {   // final layer: fold tail passthrough
        if (c < 3) Xout[1048576 + n*3 + c] = tpos[n*3 + c];
        if (c == 3) ((int*)Xout)[1048576 + NF*3 + n] = tbatch[n];
    }
}

// ---------------- chunked-path kernels (only if ws too small for full T) ----------------
__global__ __launch_bounds__(256) void msg_kernel(
    const __hip_bfloat16* __restrict__ Tc, int n0,
    const float* __restrict__ basis, const uint2* __restrict__ wi8,
    const int* __restrict__ permS, const int* __restrict__ offsS,
    int c0, int c1, const int* __restrict__ esrc,
    __hip_bfloat16* __restrict__ msg)
{
    const int eBeg = offsS[c0];
    const int eEnd = offsS[c1];
    const int lane = threadIdx.x & 63;
    const int sub  = threadIdx.x >> 6;
    for (int p = eBeg + blockIdx.x*4 + sub; p < eEnd; p += gridDim.x*4) {
        const int e = permS[p];
        const int src = esrc[e];
        const uint2 w8 = wi8[e];
        const float* bs = basis + (size_t)e*8;
        const __hip_bfloat16* Trow = Tc + (size_t)(src - n0) * TROW;
        float acc = 0.0f;
        #pragma unroll
        for (int s = 0; s < 4; ++s) {
            const int wk = (w8.x >> (8*s)) & 255;
            acc += bs[s] * __bfloat162float(Trow[wk*64 + lane]);
        }
        #pragma unroll
        for (int s = 0; s < 4; ++s) {
            const int wk = (w8.y >> (8*s)) & 255;
            acc += bs[4+s] * __bfloat162float(Trow[wk*64 + lane]);
        }
        msg[(size_t)e*64 + lane] = __float2bfloat16(acc);
    }
}

template<int KIN>
__global__ __launch_bounds__(64) void agg_msg_kernel(
    const __hip_bfloat16* __restrict__ msg, const int* __restrict__ permD,
    const int* __restrict__ offsD, const int* __restrict__ cntD,
    const float* __restrict__ X, const float* __restrict__ root,
    const float* __restrict__ bias, float* __restrict__ Xout,
    __hip_bfloat16* __restrict__ Xbout)
{
    const int n = blockIdx.x, c = threadIdx.x;
    float acc = 0.0f;
    const int beg = offsD[n], num = cntD[n];
    for (int t = 0; t < num; ++t) {
        const int e = permD[beg + t];
        acc += __bfloat162float(msg[(size_t)e*64 + c]);
    }
    const float agg = acc / fmaxf((float)num, 1.0f);
    const float* xr = X + (size_t)n * KIN;
    float r = 0.0f;
    #pragma unroll 16
    for (int i = 0; i < KIN; ++i) r = fmaf(xr[i], root[i*64 + c], r);
    float o = agg + r + bias[c];
    o = (o > 0.0f) ? o : expm1f(o);
    Xout[(size_t)n*64 + c] = o;
    if (Xbout) Xbout[(size_t)n*64 + c] = __float2bfloat16(o);
}

__global__ __launch_bounds__(256) void tail_kernel(
    const float* __restrict__ pos_skip, const int* __restrict__ batch_skip,
    float* __restrict__ out)
{
    const int i = blockIdx.x * 256 + threadIdx.x;
    if (i < NF*3) out[1048576 + i] = pos_skip[i];
    if (i < NF)   ((int*)out)[1048576 + NF*3 + i] = batch_skip[i];
}

extern "C" void kernel_launch(void* const* d_in, const int* in_sizes, int n_in,
                              void* d_out, int out_size, void* d_ws, size_t ws_size,
                              hipStream_t stream)
{
    const float* x          = (const float*)d_in[0];
    const float* pos        = (const float*)d_in[1];
    const int*   batch      = (const int*)d_in[2];
    const float* x_skip     = (const float*)d_in[3];
    const float* pos_skip   = (const float*)d_in[4];
    const int*   batch_skip = (const int*)d_in[5];
    const int*   ei         = (const int*)d_in[6];
    const float* W0    = (const float*)d_in[7];
    const float* root0 = (const float*)d_in[8];
    const float* b0    = (const float*)d_in[9];
    const float* W1    = (const float*)d_in[10];
    const float* root1 = (const float*)d_in[11];
    const float* b1    = (const float*)d_in[12];
    const float* W2    = (const float*)d_in[13];
    const float* root2 = (const float*)d_in[14];
    const float* b2    = (const float*)d_in[15];

    char* wp = (char*)d_ws;
    size_t used = 0;
    auto carve = [&](size_t bytes) {
        char* p = wp;
        size_t a = (bytes + 255) & ~(size_t)255;
        wp += a; used += a;
        return p;
    };
    float* X0    = (float*)carve((size_t)NF * 128 * 4);
    float* X1    = (float*)carve((size_t)NF * 64 * 4);
    float* X2    = (float*)carve((size_t)NF * 64 * 4);
    __hip_bfloat16* Xb0 = (__hip_bfloat16*)carve((size_t)NF * 128 * 2);
    __hip_bfloat16* Xb1 = (__hip_bfloat16*)carve((size_t)NF * 64 * 2);
    __hip_bfloat16* Xb2 = (__hip_bfloat16*)carve((size_t)NF * 64 * 2);
    __hip_bfloat16* Wt0 = (__hip_bfloat16*)carve((size_t)125 * 128 * 64 * 2);
    __hip_bfloat16* Wt1 = (__hip_bfloat16*)carve((size_t)125 * 64 * 64 * 2);
    __hip_bfloat16* Wt2 = (__hip_bfloat16*)carve((size_t)125 * 64 * 64 * 2);
    float* basis = (float*)carve((size_t)NE * 8 * 4);
    uint2* wi8   = (uint2*)carve((size_t)NE * 8);
    __hip_bfloat16* msg = (__hip_bfloat16*)carve((size_t)NE * 64 * 2);  // chunked path only
    int*   idx3  = (int*)carve((size_t)NF * 3 * 4);
    float* w3    = (float*)carve((size_t)NF * 3 * 4);
    int* zeroBase = (int*)carve((size_t)(2*NCELL + 3*NF) * 4);
    int* cellCnt  = zeroBase;
    int* qCellCnt = zeroBase + NCELL;
    int* cntD     = zeroBase + 2*NCELL;
    int* cntS     = zeroBase + 2*NCELL + NF;
    int* flags    = zeroBase + 2*NCELL + 2*NF;
    int*   cellOffs   = (int*)carve((size_t)(NCELL+1) * 4);
    int*   cellCursor = (int*)carve((size_t)NCELL * 4);
    int*   qOffs      = (int*)carve((size_t)(NCELL+1) * 4);
    int*   qCursor    = (int*)carve((size_t)NCELL * 4);
    int*   cellId  = (int*)carve((size_t)NC * 4);
    int*   qCellId = (int*)carve((size_t)NF * 4);
    int*   qIds    = (int*)carve((size_t)NF * 4);
    int*   binPts  = (int*)carve((size_t)NC * 4);
    float* binPos  = (float*)carve((size_t)NC * 3 * 4);
    int*   binBatch= (int*)carve((size_t)NC * 4);
    int*   offsD   = (int*)carve((size_t)(NF+1) * 4);
    int*   cursorD = (int*)carve((size_t)NF * 4);
    int*   permD   = (int*)carve((size_t)NE * 4);
    int*   offsS   = (int*)carve((size_t)(NF+1) * 4);
    int*   cursorS = (int*)carve((size_t)NF * 4);
    int*   permS   = (int*)carve((size_t)NE * 4);

    size_t remain = (ws_size > used) ? (ws_size - used) : 0;
    int CH = NF;
    while (CH > 512 && (size_t)CH * TROW * 2 > remain) CH >>= 1;
    const bool fullT = (CH == NF);
    __hip_bfloat16* T = (__hip_bfloat16*)wp;
    const int NCH = NF / CH;

    hipMemsetAsync(zeroBase, 0, (size_t)(2*NCELL + 3*NF) * 4, stream);
    // KNN via uniform grid (cell-centric, exact + fallback)
    hist2_kernel<<<dim3(NF/256, 2), 256, 0, stream>>>(pos, pos_skip, cellCnt, cellId, qCellCnt, qCellId);
    cellscan2_kernel<<<2, 512, 0, stream>>>(cellCnt, cellOffs, cellCursor, qCellCnt, qOffs, qCursor);
    binscat2_kernel<<<dim3(NF/256, 2), 256, 0, stream>>>(pos, batch, cellId, cellCursor,
                                                         binPts, binPos, binBatch, qCellId, qCursor, qIds);
    knn_cell_kernel<<<NCELL, 256, 0, stream>>>(binPos, binBatch, binPts, cellOffs,
                                               qIds, qOffs, pos_skip, batch_skip, idx3, w3, flags);
    knn_fallback_kernel<<<NF/4, 256, 0, stream>>>(pos, batch, pos_skip, batch_skip, flags, idx3, w3);
    interp_kernel<<<NF, 64, 0, stream>>>(x, x_skip, idx3, w3, X0, Xb0);
    // edge prep
    basis_kernel<<<NE/256, 256, 0, stream>>>(ei, pos_skip, basis, wi8, cntD, cntS);
    scan2_kernel<<<2, 1024, 0, stream>>>(cntD, offsD, cursorD, cntS, offsS, cursorS);
    scatter2_kernel<<<dim3(NE/256, 2), 256, 0, stream>>>(ei, cursorD, permD, cursorS, permS);
    wprep_all_kernel<<<dim3(125, 3), 256, 0, stream>>>(W0, W1, W2, Wt0, Wt1, Wt2);

    if (fullT) {
        gemm_mfma_kernel<128><<<dim3(125, NF/128), 256, 0, stream>>>(Xb0, Wt0, T);
        agg_fused_kernel<128><<<NF, 64, 0, stream>>>(T, basis, wi8, permD, offsD, cntD, ei,
                                                     X0, root0, b0, X1, Xb1, nullptr, nullptr);
        gemm_mfma_kernel<64><<<dim3(125, NF/128), 256, 0, stream>>>(Xb1, Wt1, T);
        agg_fused_kernel<64><<<NF, 64, 0, stream>>>(T, basis, wi8, permD, offsD, cntD, ei,
                                                    X1, root1, b1, X2, Xb2, nullptr, nullptr);
        gemm_mfma_kernel<64><<<dim3(125, NF/128), 256, 0, stream>>>(Xb2, Wt2, T);
        agg_fused_kernel<64><<<NF, 64, 0, stream>>>(T, basis, wi8, permD, offsD, cntD, ei,
                                                    X2, root2, b2, (float*)d_out, (__hip_bfloat16*)nullptr,
                                                    pos_skip, batch_skip);
    } else {
        for (int c = 0; c < NCH; ++c) {
            gemm_mfma_kernel<128><<<dim3(125, CH/128), 256, 0, stream>>>(Xb0 + (size_t)c*CH*128, Wt0, T);
            msg_kernel<<<2048, 256, 0, stream>>>(T, c*CH, basis, wi8, permS, offsS, c*CH, (c+1)*CH, ei, msg);
        }
        agg_msg_kernel<128><<<NF, 64, 0, stream>>>(msg, permD, offsD, cntD, X0, root0, b0, X1, Xb1);
        for (int c = 0; c < NCH; ++c) {
            gemm_mfma_kernel<64><<<dim3(125, CH/128), 256, 0, stream>>>(Xb1 + (size_t)c*CH*64, Wt1, T);
            msg_kernel<<<2048, 256, 0, stream>>>(T, c*CH, basis, wi8, permS, offsS, c*CH, (c+1)*CH, ei, msg);
        }
        agg_msg_kernel<64><<<NF, 64, 0, stream>>>(msg, permD, offsD, cntD, X1, root1, b1, X2, Xb2);
        for (int c = 0; c < NCH; ++c) {
            gemm_mfma_kernel<64><<<dim3(125, CH/128), 256, 0, stream>>>(Xb2 + (size_t)c*CH*64, Wt2, T);
            msg_kernel<<<2048, 256, 0, stream>>>(T, c*CH, basis, wi8, permS, offsS, c*CH, (c+1)*CH, ei, msg);
        }
        agg_msg_kernel<64><<<NF, 64, 0, stream>>>(msg, permD, offsD, cntD, X2, root2, b2, (float*)d_out, (__hip_bfloat16*)nullptr);
        tail_kernel<<<(NF*3 + 255)/256, 256, 0, stream>>>(pos_skip, batch_skip, (float*)d_out);
    }
}

// Round 9
// 647.034 us; speedup vs baseline: 1.4104x; 1.0064x over previous
//
#include <hip/hip_runtime.h>
#include <hip/hip_bf16.h>

#define NC 8192
#define NF 16384
#define NE 262144
#define TROW 8000   // 125 * 64
#define GB 8
#define NCELL 512   // GB^3
#define CELLH 0.125f
#define MAXP 1024
#define QSPLIT 4

typedef __attribute__((ext_vector_type(8))) short short8v;  // 8 bf16
typedef __attribute__((ext_vector_type(4))) float f32x4;

// ---------------- binning: histograms for points (y=0) and queries (y=1) ----------------
__global__ __launch_bounds__(256) void hist2_kernel(
    const float* __restrict__ pos, const float* __restrict__ pos_skip,
    int* __restrict__ cellCnt, int* __restrict__ cellId,
    int* __restrict__ qCellCnt, int* __restrict__ qCellId)
{
    const int i = blockIdx.x * 256 + threadIdx.x;
    if (blockIdx.y == 0) {
        if (i >= NC) return;
        const int cx = min((int)(pos[i*3+0] * GB), GB-1);
        const int cy = min((int)(pos[i*3+1] * GB), GB-1);
        const int cz = min((int)(pos[i*3+2] * GB), GB-1);
        const int cell = (cz*GB + cy)*GB + cx;
        cellId[i] = cell;
        atomicAdd(&cellCnt[cell], 1);
    } else {
        const int cx = min((int)(pos_skip[i*3+0] * GB), GB-1);
        const int cy = min((int)(pos_skip[i*3+1] * GB), GB-1);
        const int cz = min((int)(pos_skip[i*3+2] * GB), GB-1);
        const int cell = (cz*GB + cy)*GB + cx;
        qCellId[i] = cell;
        atomicAdd(&qCellCnt[cell], 1);
    }
}

// ---------------- binning: scan 512 cells x2 (block 0: points, block 1: queries) ----------------
__global__ __launch_bounds__(512) void cellscan2_kernel(
    const int* __restrict__ cellCnt, int* __restrict__ cellOffs, int* __restrict__ cellCursor,
    const int* __restrict__ qCellCnt, int* __restrict__ qOffs, int* __restrict__ qCursor)
{
    const int* cnt = blockIdx.x ? qCellCnt : cellCnt;
    int* offs   = blockIdx.x ? qOffs   : cellOffs;
    int* cursor = blockIdx.x ? qCursor : cellCursor;
    __shared__ int s[512];
    const int tid = threadIdx.x;
    const int v = cnt[tid];
    s[tid] = v;
    __syncthreads();
    for (int off = 1; off < 512; off <<= 1) {
        int t = (tid >= off) ? s[tid - off] : 0;
        __syncthreads();
        s[tid] += t;
        __syncthreads();
    }
    offs[tid] = s[tid] - v;
    cursor[tid] = s[tid] - v;
    if (tid == 511) offs[512] = s[511];
}

// ---------------- binning: scatter points (y=0) and query ids (y=1) ----------------
__global__ __launch_bounds__(256) void binscat2_kernel(
    const float* __restrict__ pos, const int* __restrict__ batch,
    const int* __restrict__ cellId, int* __restrict__ cellCursor,
    int* __restrict__ binPts, float* __restrict__ binPos, int* __restrict__ binBatch,
    const int* __restrict__ qCellId, int* __restrict__ qCursor, int* __restrict__ qIds)
{
    const int i = blockIdx.x * 256 + threadIdx.x;
    if (blockIdx.y == 0) {
        if (i >= NC) return;
        const int cell = cellId[i];
        const int p = atomicAdd(&cellCursor[cell], 1);
        binPts[p] = i;
        binPos[p*3+0] = pos[i*3+0];
        binPos[p*3+1] = pos[i*3+1];
        binPos[p*3+2] = pos[i*3+2];
        binBatch[p] = batch[i];
    } else {
        const int p = atomicAdd(&qCursor[qCellId[i]], 1);
        qIds[p] = i;
    }
}

// ---------------- KNN: QSPLIT blocks per cell, 32 lanes/query, LDS-staged hood ----------------
__global__ __launch_bounds__(256) void knn_cell_kernel(
    const float* __restrict__ binPos, const int* __restrict__ binBatch,
    const int* __restrict__ binPts, const int* __restrict__ cellOffs,
    const int* __restrict__ qIds, const int* __restrict__ qOffs,
    const float* __restrict__ pos_skip, const int* __restrict__ batch_skip,
    int* __restrict__ idx3, float* __restrict__ w3, int* __restrict__ flags)
{
    const int cell = blockIdx.x;
    const int slice = blockIdx.y;            // 0..QSPLIT-1
    const int cx = cell & 7, cy = (cell >> 3) & 7, cz = cell >> 6;
    const int tid = threadIdx.x;
    const int qBeg = qOffs[cell], qEnd = qOffs[cell+1];
    if (qBeg + slice >= qEnd) return;        // no queries for this slice

    __shared__ float lp[MAXP*3];
    __shared__ int   lb[MAXP];
    __shared__ int   li[MAXP];
    __shared__ int   rBeg[27], rCnt[27], rDst[27];
    __shared__ int   total_s;

    if (tid < 27) {
        const int zz = cz - 1 + tid/9, yy = cy - 1 + (tid/3)%3, xx = cx - 1 + tid%3;
        const bool ok = (unsigned)zz < GB && (unsigned)yy < GB && (unsigned)xx < GB;
        if (ok) {
            const int nc = (zz*GB + yy)*GB + xx;
            const int b = cellOffs[nc];
            rBeg[tid] = b;
            rCnt[tid] = cellOffs[nc+1] - b;
        } else {
            rBeg[tid] = 0; rCnt[tid] = 0;
        }
    }
    __syncthreads();
    if (tid == 0) {
        int t = 0;
        #pragma unroll
        for (int k = 0; k < 27; ++k) { rDst[k] = t; t += rCnt[k]; }
        total_s = t;
    }
    __syncthreads();
    const int total = total_s;
    if (total > MAXP) {                      // adversarial density: punt to brute force
        for (int q = qBeg + tid; q < qEnd; q += 256) flags[qIds[q]] = 1;
        return;
    }
    #pragma unroll 1
    for (int k = 0; k < 27; ++k) {
        const int b = rBeg[k], c = rCnt[k], d0 = rDst[k];
        for (int i = tid; i < c; i += 256) {
            const int p = b + i, d = d0 + i;
            lp[d*3+0] = binPos[p*3+0];
            lp[d*3+1] = binPos[p*3+1];
            lp[d*3+2] = binPos[p*3+2];
            lb[d] = binBatch[p];
            li[d] = binPts[p];
        }
    }
    __syncthreads();

    const int sub = tid & 31, g = tid >> 5;  // 8 query-groups of 32 lanes
    for (int qi = qBeg + slice + QSPLIT*g; qi < qEnd; qi += QSPLIT*8) {
        const int y = qIds[qi];
        const float px = pos_skip[y*3+0], py = pos_skip[y*3+1], pz = pos_skip[y*3+2];
        const int by = batch_skip[y];
        float b0 = INFINITY, b1 = INFINITY, b2 = INFINITY;
        int i0 = 0, i1 = 0, i2 = 0;
        auto ins = [&](float d, int gj) {
            if (d < b2) {
                if (d < b1) {
                    b2 = b1; i2 = i1;
                    if (d < b0) { b1 = b0; i1 = i0; b0 = d; i0 = gj; }
                    else        { b1 = d;  i1 = gj; }
                } else { b2 = d; i2 = gj; }
            }
        };
        for (int p = sub; p < total; p += 32) {
            const float dx = px - lp[p*3+0];
            const float dy = py - lp[p*3+1];
            const float dz = pz - lp[p*3+2];
            float d = dx*dx + dy*dy + dz*dz;
            if (lb[p] != by) d = INFINITY;
            ins(d, li[p]);
        }
        #pragma unroll
        for (int mask = 1; mask <= 16; mask <<= 1) {
            float c0 = __shfl_xor(b0, mask), c1 = __shfl_xor(b1, mask), c2 = __shfl_xor(b2, mask);
            int   j0 = __shfl_xor(i0, mask), j1 = __shfl_xor(i1, mask), j2 = __shfl_xor(i2, mask);
            ins(c0, j0); ins(c1, j1); ins(c2, j2);
        }
        if (sub == 0) {
            float rd = 1e30f;    // distance to searched-box boundary (cube faces exempt)
            if (cx > 0)    rd = fminf(rd, px - (cx-1)*CELLH);
            if (cx < GB-1) rd = fminf(rd, (cx+2)*CELLH - px);
            if (cy > 0)    rd = fminf(rd, py - (cy-1)*CELLH);
            if (cy < GB-1) rd = fminf(rd, (cy+2)*CELLH - py);
            if (cz > 0)    rd = fminf(rd, pz - (cz-1)*CELLH);
            if (cz < GB-1) rd = fminf(rd, (cz+2)*CELLH - pz);
            if (!(b2 <= rd*rd)) flags[y] = 1;   // also catches b2 == INF
            idx3[y*3+0] = i0; idx3[y*3+1] = i1; idx3[y*3+2] = i2;
            w3[y*3+0] = 1.0f / fmaxf(b0, 1e-16f);
            w3[y*3+1] = 1.0f / fmaxf(b1, 1e-16f);
            w3[y*3+2] = 1.0f / fmaxf(b2, 1e-16f);
        }
    }
}

// ---------------- KNN fallback: exact brute force for flagged queries ----------------
__global__ __launch_bounds__(256) void knn_fallback_kernel(
    const float* __restrict__ pos, const int* __restrict__ batch,
    const float* __restrict__ pos_skip, const int* __restrict__ batch_skip,
    const int* __restrict__ flags, int* __restrict__ idx3, float* __restrict__ w3)
{
    const int s = threadIdx.x & 63;
    const int y = blockIdx.x * 4 + (threadIdx.x >> 6);
    if (!flags[y]) return;
    const float px = pos_skip[y*3+0], py = pos_skip[y*3+1], pz = pos_skip[y*3+2];
    const int by = batch_skip[y];
    float b0 = INFINITY, b1 = INFINITY, b2 = INFINITY;
    int i0 = 0, i1 = 0, i2 = 0;
    auto ins = [&](float d, int gj) {
        if (d < b2) {
            if (d < b1) {
                b2 = b1; i2 = i1;
                if (d < b0) { b1 = b0; i1 = i0; b0 = d; i0 = gj; }
                else        { b1 = d;  i1 = gj; }
            } else { b2 = d; i2 = gj; }
        }
    };
    for (int j = s; j < NC; j += 64) {
        const float dx = px - pos[j*3+0];
        const float dy = py - pos[j*3+1];
        const float dz = pz - pos[j*3+2];
        float d = dx*dx + dy*dy + dz*dz;
        if (batch[j] != by) d = INFINITY;
        ins(d, j);
    }
    #pragma unroll
    for (int mask = 1; mask <= 32; mask <<= 1) {
        float c0 = __shfl_xor(b0, mask), c1 = __shfl_xor(b1, mask), c2 = __shfl_xor(b2, mask);
        int   j0 = __shfl_xor(i0, mask), j1 = __shfl_xor(i1, mask), j2 = __shfl_xor(i2, mask);
        ins(c0, j0); ins(c1, j1); ins(c2, j2);
    }
    if (s == 0) {
        idx3[y*3+0] = i0; idx3[y*3+1] = i1; idx3[y*3+2] = i2;
        w3[y*3+0] = 1.0f / fmaxf(b0, 1e-16f);
        w3[y*3+1] = 1.0f / fmaxf(b1, 1e-16f);
        w3[y*3+2] = 1.0f / fmaxf(b2, 1e-16f);
    }
}

// ---------------- interpolate + concat -> X0 fp32 + Xb0 bf16 ----------------
__global__ __launch_bounds__(64) void interp_kernel(
    const float* __restrict__ x, const float* __restrict__ x_skip,
    const int* __restrict__ idx3, const float* __restrict__ w3,
    float* __restrict__ X0, __hip_bfloat16* __restrict__ Xb0)
{
    const int n = blockIdx.x, c = threadIdx.x;
    const int j0 = idx3[n*3+0], j1 = idx3[n*3+1], j2 = idx3[n*3+2];
    const float w0 = w3[n*3+0], w1 = w3[n*3+1], w2 = w3[n*3+2];
    const float inv = 1.0f / (w0 + w1 + w2);
    const float h = (w0 * x[j0*64+c] + w1 * x[j1*64+c] + w2 * x[j2*64+c]) * inv;
    const float xs = x_skip[n*64+c];
    X0[(size_t)n*128 + c]      = h;
    X0[(size_t)n*128 + 64 + c] = xs;
    Xb0[(size_t)n*128 + c]      = __float2bfloat16(h);
    Xb0[(size_t)n*128 + 64 + c] = __float2bfloat16(xs);
}

// ---------------- spline basis per edge + src/dst histograms ----------------
__global__ __launch_bounds__(256) void basis_kernel(
    const int* __restrict__ ei, const float* __restrict__ pos_skip,
    float* __restrict__ basis, uint2* __restrict__ wi8,
    int* __restrict__ cntD, int* __restrict__ cntS)
{
    const int e = blockIdx.x * 256 + threadIdx.x;
    const int src = ei[e], dst = ei[NE + e];
    float fr[3]; int lo[3];
    #pragma unroll
    for (int d = 0; d < 3; ++d) {
        float p = (pos_skip[dst*3+d] - pos_skip[src*3+d]) * 4.0f + 0.5f;
        p = fminf(fmaxf(p, 0.0f), 1.0f);
        float v = p * 4.0f;
        float l = fminf(floorf(v), 3.0f);
        fr[d] = v - l;
        lo[d] = (int)l;
    }
    unsigned int wlo = 0, whi = 0;
    #pragma unroll
    for (int s = 0; s < 8; ++s) {
        const int bit0 = s & 1, bit1 = (s >> 1) & 1, bit2 = (s >> 2) & 1;
        float b = (bit0 ? fr[0] : 1.0f - fr[0])
                * (bit1 ? fr[1] : 1.0f - fr[1])
                * (bit2 ? fr[2] : 1.0f - fr[2]);
        int w = (lo[0] + bit0) + 5 * (lo[1] + bit1) + 25 * (lo[2] + bit2);
        basis[(size_t)e*8 + s] = b;
        if (s < 4) wlo |= ((unsigned)w) << (8*s);
        else       whi |= ((unsigned)w) << (8*(s-4));
    }
    wi8[e] = make_uint2(wlo, whi);
    atomicAdd(&cntD[dst], 1);
    atomicAdd(&cntS[src], 1);
}

// ---------------- dual exclusive scan over NF counts ----------------
__global__ __launch_bounds__(1024) void scan2_kernel(
    const int* __restrict__ cntD, int* __restrict__ offsD, int* __restrict__ curD,
    const int* __restrict__ cntS, int* __restrict__ offsS, int* __restrict__ curS)
{
    const int* cnt = blockIdx.x ? cntS : cntD;
    int* offs   = blockIdx.x ? offsS : offsD;
    int* cursor = blockIdx.x ? curS  : curD;
    __shared__ int s[1024];
    __shared__ int carry_s;
    const int tid = threadIdx.x;
    if (tid == 0) carry_s = 0;
    __syncthreads();
    for (int ch = 0; ch < NF/1024; ++ch) {
        const int i = ch*1024 + tid;
        const int v = cnt[i];
        s[tid] = v;
        __syncthreads();
        for (int off = 1; off < 1024; off <<= 1) {
            int t = (tid >= off) ? s[tid - off] : 0;
            __syncthreads();
            s[tid] += t;
            __syncthreads();
        }
        const int incl  = s[tid];
        const int total = s[1023];
        const int base  = carry_s;
        const int excl  = base + incl - v;
        offs[i] = excl; cursor[i] = excl;
        __syncthreads();
        if (tid == 0) carry_s = base + total;
        __syncthreads();
    }
    if (tid == 0) offs[NF] = carry_s;
}

// ---------------- dual scatter: y=0 dst-sorted, y=1 src-sorted ----------------
__global__ __launch_bounds__(256) void scatter2_kernel(
    const int* __restrict__ ei, int* __restrict__ curD, int* __restrict__ permD,
    int* __restrict__ curS, int* __restrict__ permS)
{
    const int e = blockIdx.x * 256 + threadIdx.x;
    if (blockIdx.y == 0) {
        const int p = atomicAdd(&curD[ei[NE + e]], 1);
        permD[p] = e;
    } else {
        const int p = atomicAdd(&curS[ei[e]], 1);
        permS[p] = e;
    }
}

// ---------------- W prep, all 3 layers: [125][KIN][64] fp32 -> [125][64][KIN] bf16 ----------------
__global__ __launch_bounds__(256) void wprep_all_kernel(
    const float* __restrict__ W0, const float* __restrict__ W1, const float* __restrict__ W2,
    __hip_bfloat16* __restrict__ Wt0, __hip_bfloat16* __restrict__ Wt1, __hip_bfloat16* __restrict__ Wt2)
{
    const int which = blockIdx.y;
    const float* W = (which == 0) ? W0 : (which == 1 ? W1 : W2);
    __hip_bfloat16* Wt = (which == 0) ? Wt0 : (which == 1 ? Wt1 : Wt2);
    const int KIN = (which == 0) ? 128 : 64;
    __shared__ float s[128*64];
    const int kern = blockIdx.x;
    const float* Wk = W + (size_t)kern * KIN * 64;
    for (int i = threadIdx.x; i < KIN*64; i += 256) s[i] = Wk[i];
    __syncthreads();
    const int nk8 = KIN/8;
    for (int i = threadIdx.x; i < 64*nk8; i += 256) {
        const int o = i / nk8, kb = (i % nk8) * 8;
        union { short8v v; __hip_bfloat16 h[8]; } u;
        #pragma unroll
        for (int j = 0; j < 8; ++j) u.h[j] = __float2bfloat16(s[(kb+j)*64 + o]);
        *(short8v*)&Wt[((size_t)kern*64 + o)*KIN + kb] = u.v;
    }
}

// ---------------- T = Xb @ W (bf16 MFMA, coalesced epilogue via LDS transpose) ----------------
template<int KIN>
__global__ __launch_bounds__(256) void gemm_mfma_kernel(
    const __hip_bfloat16* __restrict__ Xb,   // [*, KIN] bf16, chunk base pre-offset
    const __hip_bfloat16* __restrict__ Wt,   // [125][64][KIN]
    __hip_bfloat16* __restrict__ T)          // [*, 8000]
{
    constexpr int BKP = KIN + 8;
    __shared__ __hip_bfloat16 As[128*BKP];   // also reused as C-tile [128][72]
    __shared__ __hip_bfloat16 Bs[64*BKP];
    const int kern = blockIdx.x;
    const int m0   = blockIdx.y * 128;

    for (int i = threadIdx.x; i < 128*(KIN/8); i += 256) {
        const int r = i / (KIN/8), c8 = (i % (KIN/8)) * 8;
        *(short8v*)&As[r*BKP + c8] = *(const short8v*)&Xb[(size_t)(m0 + r)*KIN + c8];
    }
    const __hip_bfloat16* Wk = Wt + (size_t)kern * 64 * KIN;
    for (int i = threadIdx.x; i < 64*(KIN/8); i += 256) {
        const int r = i / (KIN/8), c8 = (i % (KIN/8)) * 8;
        *(short8v*)&Bs[r*BKP + c8] = *(const short8v*)&Wk[(size_t)r*KIN + c8];
    }
    __syncthreads();

    const int wid  = threadIdx.x >> 6;
    const int lane = threadIdx.x & 63;
    const int lr   = lane & 15;
    const int lk   = (lane >> 4) * 8;

    f32x4 acc[2][4] = {};
    #pragma unroll
    for (int ks = 0; ks < KIN/32; ++ks) {
        short8v a0 = *(const short8v*)&As[(wid*32 +      lr)*BKP + ks*32 + lk];
        short8v a1 = *(const short8v*)&As[(wid*32 + 16 + lr)*BKP + ks*32 + lk];
        #pragma unroll
        for (int n = 0; n < 4; ++n) {
            short8v b = *(const short8v*)&Bs[(n*16 + lr)*BKP + ks*32 + lk];
            acc[0][n] = __builtin_amdgcn_mfma_f32_16x16x32_bf16(a0, b, acc[0][n], 0, 0, 0);
            acc[1][n] = __builtin_amdgcn_mfma_f32_16x16x32_bf16(a1, b, acc[1][n], 0, 0, 0);
        }
    }

    // epilogue: acc -> LDS C-tile [128][72] (pad keeps banks <=2-way, 144B stride is 16B-aligned)
    __syncthreads();
    __hip_bfloat16* Ct = As;
    #pragma unroll
    for (int m = 0; m < 2; ++m) {
        const int rowL = wid*32 + m*16 + (lane >> 4)*4;
        #pragma unroll
        for (int n = 0; n < 4; ++n) {
            const int colL = n*16 + lr;
            #pragma unroll
            for (int i = 0; i < 4; ++i)
                Ct[(rowL + i)*72 + colL] = __float2bfloat16(acc[m][n][i]);
        }
    }
    __syncthreads();
    // coalesced store: 128 rows x 8 chunks of 8 bf16 = 1024 short8v stores
    const size_t tbase = (size_t)m0 * TROW + kern*64;
    #pragma unroll
    for (int u = threadIdx.x; u < 1024; u += 256) {
        const int row = u >> 3, ch = (u & 7) * 8;
        *(short8v*)&T[tbase + (size_t)row*TROW + ch] = *(short8v*)&Ct[row*72 + ch];
    }
}

// ---------------- FUSED: per-dst gather from T + mean + root + bias + ELU (+tail) ----------------
template<int KIN>
__global__ __launch_bounds__(64) void agg_fused_kernel(
    const __hip_bfloat16* __restrict__ T, const float* __restrict__ basis,
    const uint2* __restrict__ wi8, const int* __restrict__ permD,
    const int* __restrict__ offsD, const int* __restrict__ cntD,
    const int* __restrict__ esrc,
    const float* __restrict__ X, const float* __restrict__ root,
    const float* __restrict__ bias, float* __restrict__ Xout,
    __hip_bfloat16* __restrict__ Xbout,
    const float* __restrict__ tpos, const int* __restrict__ tbatch)
{
    const int n = blockIdx.x, c = threadIdx.x;
    float acc = 0.0f;
    const int beg = offsD[n], num = cntD[n];
    for (int t = 0; t < num; ++t) {
        const int e = permD[beg + t];
        const int src = esrc[e];
        const uint2 w8 = wi8[e];
        const float4 bl = *(const float4*)(basis + (size_t)e*8);
        const float4 bh = *(const float4*)(basis + (size_t)e*8 + 4);
        const __hip_bfloat16* Trow = T + (size_t)src * TROW;
        acc += bl.x * __bfloat162float(Trow[((w8.x      ) & 255)*64 + c]);
        acc += bl.y * __bfloat162float(Trow[((w8.x >>  8) & 255)*64 + c]);
        acc += bl.z * __bfloat162float(Trow[((w8.x >> 16) & 255)*64 + c]);
        acc += bl.w * __bfloat162float(Trow[((w8.x >> 24) & 255)*64 + c]);
        acc += bh.x * __bfloat162float(Trow[((w8.y      ) & 255)*64 + c]);
        acc += bh.y * __bfloat162float(Trow[((w8.y >>  8) & 255)*64 + c]);
        acc += bh.z * __bfloat162float(Trow[((w8.y >> 16) & 255)*64 + c]);
        acc += bh.w * __bfloat162float(Trow[((w8.y >> 24) & 255)*64 + c]);
    }
    const float agg = acc / fmaxf((float)num, 1.0f);
    const float* xr = X + (size_t)n * KIN;
    float r = 0.0f;
    #pragma unroll 16
    for (int i = 0; i < KIN; ++i) r = fmaf(xr[i], root[i*64 + c], r);
    float o = agg + r + bias[c];
    o = (o > 0.0f) ? o : expm1f(o);
    Xout[(size_t)n*64 + c] = o;
    if (Xbout) Xbout[(size_t)n*64 + c] = __float2bfloat16(o);
    if (tpos) {   // final layer: fold tail passthrough
        if (c < 3) Xout[1048576 + n*3 + c] = tpos[n*3 + c];
        if (c == 3) ((int*)Xout)[1048576 + NF*3 + n] = tbatch[n];
    }
}

// ---------------- chunked-path kernels (only if ws too small for full T) ----------------
__global__ __launch_bounds__(256) void msg_kernel(
    const __hip_bfloat16* __restrict__ Tc, int n0,
    const float* __restrict__ basis, const uint2* __restrict__ wi8,
    const int* __restrict__ permS, const int* __restrict__ offsS,
    int c0, int c1, const int* __restrict__ esrc,
    __hip_bfloat16* __restrict__ msg)
{
    const int eBeg = offsS[c0];
    const int eEnd = offsS[c1];
    const int lane = threadIdx.x & 63;
    const int sub  = threadIdx.x >> 6;
    for (int p = eBeg + blockIdx.x*4 + sub; p < eEnd; p += gridDim.x*4) {
        const int e = permS[p];
        const int src = esrc[e];
        const uint2 w8 = wi8[e];
        const float* bs = basis + (size_t)e*8;
        const __hip_bfloat16* Trow = Tc + (size_t)(src - n0) * TROW;
        float acc = 0.0f;
        #pragma unroll
        for (int s = 0; s < 4; ++s) {
            const int wk = (w8.x >> (8*s)) & 255;
            acc += bs[s] * __bfloat162float(Trow[wk*64 + lane]);
        }
        #pragma unroll
        for (int s = 0; s < 4; ++s) {
            const int wk = (w8.y >> (8*s)) & 255;
            acc += bs[4+s] * __bfloat162float(Trow[wk*64 + lane]);
        }
        msg[(size_t)e*64 + lane] = __float2bfloat16(acc);
    }
}

template<int KIN>
__global__ __launch_bounds__(64) void agg_msg_kernel(
    const __hip_bfloat16* __restrict__ msg, const int* __restrict__ permD,
    const int* __restrict__ offsD, const int* __restrict__ cntD,
    const float* __restrict__ X, const float* __restrict__ root,
    const float* __restrict__ bias, float* __restrict__ Xout,
    __hip_bfloat16* __restrict__ Xbout)
{
    const int n = blockIdx.x, c = threadIdx.x;
    float acc = 0.0f;
    const int beg = offsD[n], num = cntD[n];
    for (int t = 0; t < num; ++t) {
        const int e = permD[beg + t];
        acc += __bfloat162float(msg[(size_t)e*64 + c]);
    }
    const float agg = acc / fmaxf((float)num, 1.0f);
    const float* xr = X + (size_t)n * KIN;
    float r = 0.0f;
    #pragma unroll 16
    for (int i = 0; i < KIN; ++i) r = fmaf(xr[i], root[i*64 + c], r);
    float o = agg + r + bias[c];
    o = (o > 0.0f) ? o : expm1f(o);
    Xout[(size_t)n*64 + c] = o;
    if (Xbout) Xbout[(size_t)n*64 + c] = __float2bfloat16(o);
}

__global__ __launch_bounds__(256) void tail_kernel(
    const float* __restrict__ pos_skip, const int* __restrict__ batch_skip,
    float* __restrict__ out)
{
    const int i = blockIdx.x * 256 + threadIdx.x;
    if (i < NF*3) out[1048576 + i] = pos_skip[i];
    if (i < NF)   ((int*)out)[1048576 + NF*3 + i] = batch_skip[i];
}

extern "C" void kernel_launch(void* const* d_in, const int* in_sizes, int n_in,
                              void* d_out, int out_size, void* d_ws, size_t ws_size,
                              hipStream_t stream)
{
    const float* x          = (const float*)d_in[0];
    const float* pos        = (const float*)d_in[1];
    const int*   batch      = (const int*)d_in[2];
    const float* x_skip     = (const float*)d_in[3];
    const float* pos_skip   = (const float*)d_in[4];
    const int*   batch_skip = (const int*)d_in[5];
    const int*   ei         = (const int*)d_in[6];
    const float* W0    = (const float*)d_in[7];
    const float* root0 = (const float*)d_in[8];
    const float* b0    = (const float*)d_in[9];
    const float* W1    = (const float*)d_in[10];
    const float* root1 = (const float*)d_in[11];
    const float* b1    = (const float*)d_in[12];
    const float* W2    = (const float*)d_in[13];
    const float* root2 = (const float*)d_in[14];
    const float* b2    = (const float*)d_in[15];

    char* wp = (char*)d_ws;
    size_t used = 0;
    auto carve = [&](size_t bytes) {
        char* p = wp;
        size_t a = (bytes + 255) & ~(size_t)255;
        wp += a; used += a;
        return p;
    };
    float* X0    = (float*)carve((size_t)NF * 128 * 4);
    float* X1    = (float*)carve((size_t)NF * 64 * 4);
    float* X2    = (float*)carve((size_t)NF * 64 * 4);
    __hip_bfloat16* Xb0 = (__hip_bfloat16*)carve((size_t)NF * 128 * 2);
    __hip_bfloat16* Xb1 = (__hip_bfloat16*)carve((size_t)NF * 64 * 2);
    __hip_bfloat16* Xb2 = (__hip_bfloat16*)carve((size_t)NF * 64 * 2);
    __hip_bfloat16* Wt0 = (__hip_bfloat16*)carve((size_t)125 * 128 * 64 * 2);
    __hip_bfloat16* Wt1 = (__hip_bfloat16*)carve((size_t)125 * 64 * 64 * 2);
    __hip_bfloat16* Wt2 = (__hip_bfloat16*)carve((size_t)125 * 64 * 64 * 2);
    float* basis = (float*)carve((size_t)NE * 8 * 4);
    uint2* wi8   = (uint2*)carve((size_t)NE * 8);
    __hip_bfloat16* msg = (__hip_bfloat16*)carve((size_t)NE * 64 * 2);  // chunked path only
    int*   idx3  = (int*)carve((size_t)NF * 3 * 4);
    float* w3    = (float*)carve((size_t)NF * 3 * 4);
    int* zeroBase = (int*)carve((size_t)(2*NCELL + 3*NF) * 4);
    int* cellCnt  = zeroBase;
    int* qCellCnt = zeroBase + NCELL;
    int* cntD     = zeroBase + 2*NCELL;
    int* cntS     = zeroBase + 2*NCELL + NF;
    int* flags    = zeroBase + 2*NCELL + 2*NF;
    int*   cellOffs   = (int*)carve((size_t)(NCELL+1) * 4);
    int*   cellCursor = (int*)carve((size_t)NCELL * 4);
    int*   qOffs      = (int*)carve((size_t)(NCELL+1) * 4);
    int*   qCursor    = (int*)carve((size_t)NCELL * 4);
    int*   cellId  = (int*)carve((size_t)NC * 4);
    int*   qCellId = (int*)carve((size_t)NF * 4);
    int*   qIds    = (int*)carve((size_t)NF * 4);
    int*   binPts  = (int*)carve((size_t)NC * 4);
    float* binPos  = (float*)carve((size_t)NC * 3 * 4);
    int*   binBatch= (int*)carve((size_t)NC * 4);
    int*   offsD   = (int*)carve((size_t)(NF+1) * 4);
    int*   cursorD = (int*)carve((size_t)NF * 4);
    int*   permD   = (int*)carve((size_t)NE * 4);
    int*   offsS   = (int*)carve((size_t)(NF+1) * 4);
    int*   cursorS = (int*)carve((size_t)NF * 4);
    int*   permS   = (int*)carve((size_t)NE * 4);

    size_t remain = (ws_size > used) ? (ws_size - used) : 0;
    int CH = NF;
    while (CH > 512 && (size_t)CH * TROW * 2 > remain) CH >>= 1;
    const bool fullT = (CH == NF);
    __hip_bfloat16* T = (__hip_bfloat16*)wp;
    const int NCH = NF / CH;

    hipMemsetAsync(zeroBase, 0, (size_t)(2*NCELL + 3*NF) * 4, stream);
    // KNN via uniform grid (cell-centric, exact + fallback)
    hist2_kernel<<<dim3(NF/256, 2), 256, 0, stream>>>(pos, pos_skip, cellCnt, cellId, qCellCnt, qCellId);
    cellscan2_kernel<<<2, 512, 0, stream>>>(cellCnt, cellOffs, cellCursor, qCellCnt, qOffs, qCursor);
    binscat2_kernel<<<dim3(NF/256, 2), 256, 0, stream>>>(pos, batch, cellId, cellCursor,
                                                         binPts, binPos, binBatch, qCellId, qCursor, qIds);
    knn_cell_kernel<<<dim3(NCELL, QSPLIT), 256, 0, stream>>>(binPos, binBatch, binPts, cellOffs,
                                                             qIds, qOffs, pos_skip, batch_skip, idx3, w3, flags);
    knn_fallback_kernel<<<NF/4, 256, 0, stream>>>(pos, batch, pos_skip, batch_skip, flags, idx3, w3);
    interp_kernel<<<NF, 64, 0, stream>>>(x, x_skip, idx3, w3, X0, Xb0);
    // edge prep
    basis_kernel<<<NE/256, 256, 0, stream>>>(ei, pos_skip, basis, wi8, cntD, cntS);
    scan2_kernel<<<2, 1024, 0, stream>>>(cntD, offsD, cursorD, cntS, offsS, cursorS);
    scatter2_kernel<<<dim3(NE/256, 2), 256, 0, stream>>>(ei, cursorD, permD, cursorS, permS);
    wprep_all_kernel<<<dim3(125, 3), 256, 0, stream>>>(W0, W1, W2, Wt0, Wt1, Wt2);

    if (fullT) {
        gemm_mfma_kernel<128><<<dim3(125, NF/128), 256, 0, stream>>>(Xb0, Wt0, T);
        agg_fused_kernel<128><<<NF, 64, 0, stream>>>(T, basis, wi8, permD, offsD, cntD, ei,
                                                     X0, root0, b0, X1, Xb1, nullptr, nullptr);
        gemm_mfma_kernel<64><<<dim3(125, NF/128), 256, 0, stream>>>(Xb1, Wt1, T);
        agg_fused_kernel<64><<<NF, 64, 0, stream>>>(T, basis, wi8, permD, offsD, cntD, ei,
                                                    X1, root1, b1, X2, Xb2, nullptr, nullptr);
        gemm_mfma_kernel<64><<<dim3(125, NF/128), 256, 0, stream>>>(Xb2, Wt2, T);
        agg_fused_kernel<64><<<NF, 64, 0, stream>>>(T, basis, wi8, permD, offsD, cntD, ei,
                                                    X2, root2, b2, (float*)d_out, (__hip_bfloat16*)nullptr,
                                                    pos_skip, batch_skip);
    } else {
        for (int c = 0; c < NCH; ++c) {
            gemm_mfma_kernel<128><<<dim3(125, CH/128), 256, 0, stream>>>(Xb0 + (size_t)c*CH*128, Wt0, T);
            msg_kernel<<<2048, 256, 0, stream>>>(T, c*CH, basis, wi8, permS, offsS, c*CH, (c+1)*CH, ei, msg);
        }
        agg_msg_kernel<128><<<NF, 64, 0, stream>>>(msg, permD, offsD, cntD, X0, root0, b0, X1, Xb1);
        for (int c = 0; c < NCH; ++c) {
            gemm_mfma_kernel<64><<<dim3(125, CH/128), 256, 0, stream>>>(Xb1 + (size_t)c*CH*64, Wt1, T);
            msg_kernel<<<2048, 256, 0, stream>>>(T, c*CH, basis, wi8, permS, offsS, c*CH, (c+1)*CH, ei, msg);
        }
        agg_msg_kernel<64><<<NF, 64, 0, stream>>>(msg, permD, offsD, cntD, X1, root1, b1, X2, Xb2);
        for (int c = 0; c < NCH; ++c) {
            gemm_mfma_kernel<64><<<dim3(125, CH/128), 256, 0, stream>>>(Xb2 + (size_t)c*CH*64, Wt2, T);
            msg_kernel<<<2048, 256, 0, stream>>>(T, c*CH, basis, wi8, permS, offsS, c*CH, (c+1)*CH, ei, msg);
        }
        agg_msg_kernel<64><<<NF, 64, 0, stream>>>(msg, permD, offsD, cntD, X2, root2, b2, (float*)d_out, (__hip_bfloat16*)nullptr);
        tail_kernel<<<(NF*3 + 255)/256, 256, 0, stream>>>(pos_skip, batch_skip, (float*)d_out);
    }
}

// Round 10
// 634.178 us; speedup vs baseline: 1.4390x; 1.0203x over previous
//
#include <hip/hip_runtime.h>
#include <hip/hip_bf16.h>

#define NC 8192
#define NF 16384
#define NE 262144
#define TROW 8000   // 125 * 64
#define GB 8
#define NCELL 512   // GB^3
#define CELLH 0.125f

typedef __attribute__((ext_vector_type(8))) short short8v;  // 8 bf16
typedef __attribute__((ext_vector_type(4))) float f32x4;

// ---------------- binning: histogram over coarse points ----------------
__global__ __launch_bounds__(256) void bin_hist_kernel(
    const float* __restrict__ pos, int* __restrict__ cellCnt, int* __restrict__ cellId)
{
    const int i = blockIdx.x * 256 + threadIdx.x;
    const int cx = min((int)(pos[i*3+0] * GB), GB-1);
    const int cy = min((int)(pos[i*3+1] * GB), GB-1);
    const int cz = min((int)(pos[i*3+2] * GB), GB-1);
    const int cell = (cz*GB + cy)*GB + cx;
    cellId[i] = cell;
    atomicAdd(&cellCnt[cell], 1);
}

// ---------------- binning: scan 512 cells (writes sentinel) ----------------
__global__ __launch_bounds__(512) void bin_scan_kernel(
    const int* __restrict__ cellCnt, int* __restrict__ cellOffs, int* __restrict__ cellCursor)
{
    __shared__ int s[512];
    const int tid = threadIdx.x;
    const int v = cellCnt[tid];
    s[tid] = v;
    __syncthreads();
    for (int off = 1; off < 512; off <<= 1) {
        int t = (tid >= off) ? s[tid - off] : 0;
        __syncthreads();
        s[tid] += t;
        __syncthreads();
    }
    cellOffs[tid] = s[tid] - v;
    cellCursor[tid] = s[tid] - v;
    if (tid == 511) cellOffs[512] = s[511];
}

// ---------------- binning: scatter points -> packed float4 (xyz + batch bits) ----------------
__global__ __launch_bounds__(256) void bin_scatter_kernel(
    const float* __restrict__ pos, const int* __restrict__ batch,
    const int* __restrict__ cellId, int* __restrict__ cellCursor,
    int* __restrict__ binPts, float4* __restrict__ binPB)
{
    const int i = blockIdx.x * 256 + threadIdx.x;
    const int cell = cellId[i];
    const int p = atomicAdd(&cellCursor[cell], 1);
    binPts[p] = i;
    float4 q;
    q.x = pos[i*3+0]; q.y = pos[i*3+1]; q.z = pos[i*3+2];
    q.w = __int_as_float(batch[i]);
    binPB[p] = q;
}

// ---------------- KNN: one wave per query, 9 contiguous ranges, no LDS ----------------
__global__ __launch_bounds__(256) void knn_wave_kernel(
    const float4* __restrict__ binPB, const int* __restrict__ binPts,
    const int* __restrict__ cellOffs,
    const float* __restrict__ pos_skip, const int* __restrict__ batch_skip,
    int* __restrict__ idx3, float* __restrict__ w3, int* __restrict__ flags)
{
    const int lane = threadIdx.x & 63;
    const int y = blockIdx.x * 4 + (threadIdx.x >> 6);
    const float px = pos_skip[y*3+0], py = pos_skip[y*3+1], pz = pos_skip[y*3+2];
    const int by = batch_skip[y];
    const int cx = min((int)(px * GB), GB-1);
    const int cy = min((int)(py * GB), GB-1);
    const int cz = min((int)(pz * GB), GB-1);
    const int xlo = max(cx-1,0), xhi = min(cx+1,GB-1);
    const int ylo = max(cy-1,0), yhi = min(cy+1,GB-1);
    const int zlo = max(cz-1,0), zhi = min(cz+1,GB-1);

    float b0 = INFINITY, b1 = INFINITY, b2 = INFINITY;
    int i0 = 0, i1 = 0, i2 = 0;
    auto ins = [&](float d, int gj) {
        if (d < b2) {
            if (d < b1) {
                b2 = b1; i2 = i1;
                if (d < b0) { b1 = b0; i1 = i0; b0 = d; i0 = gj; }
                else        { b1 = d;  i1 = gj; }
            } else { b2 = d; i2 = gj; }
        }
    };

    // 3x3 rows in (z,y); x-range is contiguous in cell id -> one range per row
    for (int zz = zlo; zz <= zhi; ++zz)
    for (int yy = ylo; yy <= yhi; ++yy) {
        const int rowb = (zz*GB + yy)*GB;
        const int b = cellOffs[rowb + xlo];
        const int e = cellOffs[rowb + xhi + 1];
        for (int p = b + lane; p < e; p += 64) {
            const float4 q = binPB[p];
            const float dx = px - q.x, dy = py - q.y, dz = pz - q.z;
            float d = dx*dx + dy*dy + dz*dz;
            if (__float_as_int(q.w) != by) d = INFINITY;
            ins(d, binPts[p]);
        }
    }
    // butterfly merge across 64 lanes (partners always hold disjoint candidate sets)
    #pragma unroll
    for (int mask = 1; mask <= 32; mask <<= 1) {
        float c0 = __shfl_xor(b0, mask), c1 = __shfl_xor(b1, mask), c2 = __shfl_xor(b2, mask);
        int   j0 = __shfl_xor(i0, mask), j1 = __shfl_xor(i1, mask), j2 = __shfl_xor(i2, mask);
        ins(c0, j0); ins(c1, j1); ins(c2, j2);
    }
    if (lane == 0) {
        float rd = 1e30f;    // distance to searched-box boundary (cube faces exempt)
        if (cx > 0)    rd = fminf(rd, px - (cx-1)*CELLH);
        if (cx < GB-1) rd = fminf(rd, (cx+2)*CELLH - px);
        if (cy > 0)    rd = fminf(rd, py - (cy-1)*CELLH);
        if (cy < GB-1) rd = fminf(rd, (cy+2)*CELLH - py);
        if (cz > 0)    rd = fminf(rd, pz - (cz-1)*CELLH);
        if (cz < GB-1) rd = fminf(rd, (cz+2)*CELLH - pz);
        if (!(b2 <= rd*rd)) flags[y] = 1;   // also catches b2 == INF
        idx3[y*3+0] = i0; idx3[y*3+1] = i1; idx3[y*3+2] = i2;
        w3[y*3+0] = 1.0f / fmaxf(b0, 1e-16f);
        w3[y*3+1] = 1.0f / fmaxf(b1, 1e-16f);
        w3[y*3+2] = 1.0f / fmaxf(b2, 1e-16f);
    }
}

// ---------------- KNN fallback: exact brute force for flagged queries ----------------
__global__ __launch_bounds__(256) void knn_fallback_kernel(
    const float* __restrict__ pos, const int* __restrict__ batch,
    const float* __restrict__ pos_skip, const int* __restrict__ batch_skip,
    const int* __restrict__ flags, int* __restrict__ idx3, float* __restrict__ w3)
{
    const int s = threadIdx.x & 63;
    const int y = blockIdx.x * 4 + (threadIdx.x >> 6);
    if (!flags[y]) return;
    const float px = pos_skip[y*3+0], py = pos_skip[y*3+1], pz = pos_skip[y*3+2];
    const int by = batch_skip[y];
    float b0 = INFINITY, b1 = INFINITY, b2 = INFINITY;
    int i0 = 0, i1 = 0, i2 = 0;
    auto ins = [&](float d, int gj) {
        if (d < b2) {
            if (d < b1) {
                b2 = b1; i2 = i1;
                if (d < b0) { b1 = b0; i1 = i0; b0 = d; i0 = gj; }
                else        { b1 = d;  i1 = gj; }
            } else { b2 = d; i2 = gj; }
        }
    };
    for (int j = s; j < NC; j += 64) {
        const float dx = px - pos[j*3+0];
        const float dy = py - pos[j*3+1];
        const float dz = pz - pos[j*3+2];
        float d = dx*dx + dy*dy + dz*dz;
        if (batch[j] != by) d = INFINITY;
        ins(d, j);
    }
    #pragma unroll
    for (int mask = 1; mask <= 32; mask <<= 1) {
        float c0 = __shfl_xor(b0, mask), c1 = __shfl_xor(b1, mask), c2 = __shfl_xor(b2, mask);
        int   j0 = __shfl_xor(i0, mask), j1 = __shfl_xor(i1, mask), j2 = __shfl_xor(i2, mask);
        ins(c0, j0); ins(c1, j1); ins(c2, j2);
    }
    if (s == 0) {
        idx3[y*3+0] = i0; idx3[y*3+1] = i1; idx3[y*3+2] = i2;
        w3[y*3+0] = 1.0f / fmaxf(b0, 1e-16f);
        w3[y*3+1] = 1.0f / fmaxf(b1, 1e-16f);
        w3[y*3+2] = 1.0f / fmaxf(b2, 1e-16f);
    }
}

// ---------------- interpolate + concat -> X0 fp32 + Xb0 bf16 ----------------
__global__ __launch_bounds__(64) void interp_kernel(
    const float* __restrict__ x, const float* __restrict__ x_skip,
    const int* __restrict__ idx3, const float* __restrict__ w3,
    float* __restrict__ X0, __hip_bfloat16* __restrict__ Xb0)
{
    const int n = blockIdx.x, c = threadIdx.x;
    const int j0 = idx3[n*3+0], j1 = idx3[n*3+1], j2 = idx3[n*3+2];
    const float w0 = w3[n*3+0], w1 = w3[n*3+1], w2 = w3[n*3+2];
    const float inv = 1.0f / (w0 + w1 + w2);
    const float h = (w0 * x[j0*64+c] + w1 * x[j1*64+c] + w2 * x[j2*64+c]) * inv;
    const float xs = x_skip[n*64+c];
    X0[(size_t)n*128 + c]      = h;
    X0[(size_t)n*128 + 64 + c] = xs;
    Xb0[(size_t)n*128 + c]      = __float2bfloat16(h);
    Xb0[(size_t)n*128 + 64 + c] = __float2bfloat16(xs);
}

// ---------------- spline basis per edge + src/dst histograms ----------------
__global__ __launch_bounds__(256) void basis_kernel(
    const int* __restrict__ ei, const float* __restrict__ pos_skip,
    float* __restrict__ basis, uint2* __restrict__ wi8,
    int* __restrict__ cntD, int* __restrict__ cntS)
{
    const int e = blockIdx.x * 256 + threadIdx.x;
    const int src = ei[e], dst = ei[NE + e];
    float fr[3]; int lo[3];
    #pragma unroll
    for (int d = 0; d < 3; ++d) {
        float p = (pos_skip[dst*3+d] - pos_skip[src*3+d]) * 4.0f + 0.5f;
        p = fminf(fmaxf(p, 0.0f), 1.0f);
        float v = p * 4.0f;
        float l = fminf(floorf(v), 3.0f);
        fr[d] = v - l;
        lo[d] = (int)l;
    }
    unsigned int wlo = 0, whi = 0;
    #pragma unroll
    for (int s = 0; s < 8; ++s) {
        const int bit0 = s & 1, bit1 = (s >> 1) & 1, bit2 = (s >> 2) & 1;
        float b = (bit0 ? fr[0] : 1.0f - fr[0])
                * (bit1 ? fr[1] : 1.0f - fr[1])
                * (bit2 ? fr[2] : 1.0f - fr[2]);
        int w = (lo[0] + bit0) + 5 * (lo[1] + bit1) + 25 * (lo[2] + bit2);
        basis[(size_t)e*8 + s] = b;
        if (s < 4) wlo |= ((unsigned)w) << (8*s);
        else       whi |= ((unsigned)w) << (8*(s-4));
    }
    wi8[e] = make_uint2(wlo, whi);
    atomicAdd(&cntD[dst], 1);
    atomicAdd(&cntS[src], 1);
}

// ---------------- dual exclusive scan over NF counts ----------------
__global__ __launch_bounds__(1024) void scan2_kernel(
    const int* __restrict__ cntD, int* __restrict__ offsD, int* __restrict__ curD,
    const int* __restrict__ cntS, int* __restrict__ offsS, int* __restrict__ curS)
{
    const int* cnt = blockIdx.x ? cntS : cntD;
    int* offs   = blockIdx.x ? offsS : offsD;
    int* cursor = blockIdx.x ? curS  : curD;
    __shared__ int s[1024];
    __shared__ int carry_s;
    const int tid = threadIdx.x;
    if (tid == 0) carry_s = 0;
    __syncthreads();
    for (int ch = 0; ch < NF/1024; ++ch) {
        const int i = ch*1024 + tid;
        const int v = cnt[i];
        s[tid] = v;
        __syncthreads();
        for (int off = 1; off < 1024; off <<= 1) {
            int t = (tid >= off) ? s[tid - off] : 0;
            __syncthreads();
            s[tid] += t;
            __syncthreads();
        }
        const int incl  = s[tid];
        const int total = s[1023];
        const int base  = carry_s;
        const int excl  = base + incl - v;
        offs[i] = excl; cursor[i] = excl;
        __syncthreads();
        if (tid == 0) carry_s = base + total;
        __syncthreads();
    }
    if (tid == 0) offs[NF] = carry_s;
}

// ---------------- dual scatter: y=0 dst-sorted, y=1 src-sorted ----------------
__global__ __launch_bounds__(256) void scatter2_kernel(
    const int* __restrict__ ei, int* __restrict__ curD, int* __restrict__ permD,
    int* __restrict__ curS, int* __restrict__ permS)
{
    const int e = blockIdx.x * 256 + threadIdx.x;
    if (blockIdx.y == 0) {
        const int p = atomicAdd(&curD[ei[NE + e]], 1);
        permD[p] = e;
    } else {
        const int p = atomicAdd(&curS[ei[e]], 1);
        permS[p] = e;
    }
}

// ---------------- W prep, all 3 layers: [125][KIN][64] fp32 -> [125][64][KIN] bf16 ----------------
__global__ __launch_bounds__(256) void wprep_all_kernel(
    const float* __restrict__ W0, const float* __restrict__ W1, const float* __restrict__ W2,
    __hip_bfloat16* __restrict__ Wt0, __hip_bfloat16* __restrict__ Wt1, __hip_bfloat16* __restrict__ Wt2)
{
    const int which = blockIdx.y;
    const float* W = (which == 0) ? W0 : (which == 1 ? W1 : W2);
    __hip_bfloat16* Wt = (which == 0) ? Wt0 : (which == 1 ? Wt1 : Wt2);
    const int KIN = (which == 0) ? 128 : 64;
    __shared__ float s[128*64];
    const int kern = blockIdx.x;
    const float* Wk = W + (size_t)kern * KIN * 64;
    for (int i = threadIdx.x; i < KIN*64; i += 256) s[i] = Wk[i];
    __syncthreads();
    const int nk8 = KIN/8;
    for (int i = threadIdx.x; i < 64*nk8; i += 256) {
        const int o = i / nk8, kb = (i % nk8) * 8;
        union { short8v v; __hip_bfloat16 h[8]; } u;
        #pragma unroll
        for (int j = 0; j < 8; ++j) u.h[j] = __float2bfloat16(s[(kb+j)*64 + o]);
        *(short8v*)&Wt[((size_t)kern*64 + o)*KIN + kb] = u.v;
    }
}

// ---------------- T = Xb @ W (bf16 MFMA, coalesced epilogue via LDS transpose) ----------------
template<int KIN>
__global__ __launch_bounds__(256) void gemm_mfma_kernel(
    const __hip_bfloat16* __restrict__ Xb,   // [*, KIN] bf16, chunk base pre-offset
    const __hip_bfloat16* __restrict__ Wt,   // [125][64][KIN]
    __hip_bfloat16* __restrict__ T)          // [*, 8000]
{
    constexpr int BKP = KIN + 8;
    __shared__ __hip_bfloat16 As[128*BKP];   // also reused as C-tile [128][72]
    __shared__ __hip_bfloat16 Bs[64*BKP];
    const int kern = blockIdx.x;
    const int m0   = blockIdx.y * 128;

    for (int i = threadIdx.x; i < 128*(KIN/8); i += 256) {
        const int r = i / (KIN/8), c8 = (i % (KIN/8)) * 8;
        *(short8v*)&As[r*BKP + c8] = *(const short8v*)&Xb[(size_t)(m0 + r)*KIN + c8];
    }
    const __hip_bfloat16* Wk = Wt + (size_t)kern * 64 * KIN;
    for (int i = threadIdx.x; i < 64*(KIN/8); i += 256) {
        const int r = i / (KIN/8), c8 = (i % (KIN/8)) * 8;
        *(short8v*)&Bs[r*BKP + c8] = *(const short8v*)&Wk[(size_t)r*KIN + c8];
    }
    __syncthreads();

    const int wid  = threadIdx.x >> 6;
    const int lane = threadIdx.x & 63;
    const int lr   = lane & 15;
    const int lk   = (lane >> 4) * 8;

    f32x4 acc[2][4] = {};
    #pragma unroll
    for (int ks = 0; ks < KIN/32; ++ks) {
        short8v a0 = *(const short8v*)&As[(wid*32 +      lr)*BKP + ks*32 + lk];
        short8v a1 = *(const short8v*)&As[(wid*32 + 16 + lr)*BKP + ks*32 + lk];
        #pragma unroll
        for (int n = 0; n < 4; ++n) {
            short8v b = *(const short8v*)&Bs[(n*16 + lr)*BKP + ks*32 + lk];
            acc[0][n] = __builtin_amdgcn_mfma_f32_16x16x32_bf16(a0, b, acc[0][n], 0, 0, 0);
            acc[1][n] = __builtin_amdgcn_mfma_f32_16x16x32_bf16(a1, b, acc[1][n], 0, 0, 0);
        }
    }

    // epilogue: acc -> LDS C-tile [128][72], then coalesced 16B stores
    __syncthreads();
    __hip_bfloat16* Ct = As;
    #pragma unroll
    for (int m = 0; m < 2; ++m) {
        const int rowL = wid*32 + m*16 + (lane >> 4)*4;
        #pragma unroll
        for (int n = 0; n < 4; ++n) {
            const int colL = n*16 + lr;
            #pragma unroll
            for (int i = 0; i < 4; ++i)
                Ct[(rowL + i)*72 + colL] = __float2bfloat16(acc[m][n][i]);
        }
    }
    __syncthreads();
    const size_t tbase = (size_t)m0 * TROW + kern*64;
    #pragma unroll
    for (int u = threadIdx.x; u < 1024; u += 256) {
        const int row = u >> 3, ch = (u & 7) * 8;
        *(short8v*)&T[tbase + (size_t)row*TROW + ch] = *(short8v*)&Ct[row*72 + ch];
    }
}

// ---------------- FUSED: per-dst gather from T + mean + root + bias + ELU (+tail) ----------------
template<int KIN>
__global__ __launch_bounds__(64) void agg_fused_kernel(
    const __hip_bfloat16* __restrict__ T, const float* __restrict__ basis,
    const uint2* __restrict__ wi8, const int* __restrict__ permD,
    const int* __restrict__ offsD, const int* __restrict__ cntD,
    const int* __restrict__ esrc,
    const float* __restrict__ X, const float* __restrict__ root,
    const float* __restrict__ bias, float* __restrict__ Xout,
    __hip_bfloat16* __restrict__ Xbout,
    const float* __restrict__ tpos, const int* __restrict__ tbatch)
{
    const int n = blockIdx.x, c = threadIdx.x;
    float acc = 0.0f;
    const int beg = offsD[n], num = cntD[n];
    for (int t = 0; t < num; ++t) {
        const int e = permD[beg + t];
        const int src = esrc[e];
        const uint2 w8 = wi8[e];
        const float4 bl = *(const float4*)(basis + (size_t)e*8);
        const float4 bh = *(const float4*)(basis + (size_t)e*8 + 4);
        const __hip_bfloat16* Trow = T + (size_t)src * TROW;
        acc += bl.x * __bfloat162float(Trow[((w8.x      ) & 255)*64 + c]);
        acc += bl.y * __bfloat162float(Trow[((w8.x >>  8) & 255)*64 + c]);
        acc += bl.z * __bfloat162float(Trow[((w8.x >> 16) & 255)*64 + c]);
        acc += bl.w * __bfloat162float(Trow[((w8.x >> 24) & 255)*64 + c]);
        acc += bh.x * __bfloat162float(Trow[((w8.y      ) & 255)*64 + c]);
        acc += bh.y * __bfloat162float(Trow[((w8.y >>  8) & 255)*64 + c]);
        acc += bh.z * __bfloat162float(Trow[((w8.y >> 16) & 255)*64 + c]);
        acc += bh.w * __bfloat162float(Trow[((w8.y >> 24) & 255)*64 + c]);
    }
    const float agg = acc / fmaxf((float)num, 1.0f);
    const float* xr = X + (size_t)n * KIN;
    float r = 0.0f;
    #pragma unroll 16
    for (int i = 0; i < KIN; ++i) r = fmaf(xr[i], root[i*64 + c], r);
    float o = agg + r + bias[c];
    o = (o > 0.0f) ? o : expm1f(o);
    Xout[(size_t)n*64 + c] = o;
    if (Xbout) Xbout[(size_t)n*64 + c] = __float2bfloat16(o);
    if (tpos) {   // final layer: fold tail passthrough
        if (c < 3) Xout[1048576 + n*3 + c] = tpos[n*3 + c];
        if (c == 3) ((int*)Xout)[1048576 + NF*3 + n] = tbatch[n];
    }
}

// ---------------- chunked-path kernels (only if ws too small for full T) ----------------
__global__ __launch_bounds__(256) void msg_kernel(
    const __hip_bfloat16* __restrict__ Tc, int n0,
    const float* __restrict__ basis, const uint2* __restrict__ wi8,
    const int* __restrict__ permS, const int* __restrict__ offsS,
    int c0, int c1, const int* __restrict__ esrc,
    __hip_bfloat16* __restrict__ msg)
{
    const int eBeg = offsS[c0];
    const int eEnd = offsS[c1];
    const int lane = threadIdx.x & 63;
    const int sub  = threadIdx.x >> 6;
    for (int p = eBeg + blockIdx.x*4 + sub; p < eEnd; p += gridDim.x*4) {
        const int e = permS[p];
        const int src = esrc[e];
        const uint2 w8 = wi8[e];
        const float* bs = basis + (size_t)e*8;
        const __hip_bfloat16* Trow = Tc + (size_t)(src - n0) * TROW;
        float acc = 0.0f;
        #pragma unroll
        for (int s = 0; s < 4; ++s) {
            const int wk = (w8.x >> (8*s)) & 255;
            acc += bs[s] * __bfloat162float(Trow[wk*64 + lane]);
        }
        #pragma unroll
        for (int s = 0; s < 4; ++s) {
            const int wk = (w8.y >> (8*s)) & 255;
            acc += bs[4+s] * __bfloat162float(Trow[wk*64 + lane]);
        }
        msg[(size_t)e*64 + lane] = __float2bfloat16(acc);
    }
}

template<int KIN>
__global__ __launch_bounds__(64) void agg_msg_kernel(
    const __hip_bfloat16* __restrict__ msg, const int* __restrict__ permD,
    const int* __restrict__ offsD, const int* __restrict__ cntD,
    const float* __restrict__ X, const float* __restrict__ root,
    const float* __restrict__ bias, float* __restrict__ Xout,
    __hip_bfloat16* __restrict__ Xbout)
{
    const int n = blockIdx.x, c = threadIdx.x;
    float acc = 0.0f;
    const int beg = offsD[n], num = cntD[n];
    for (int t = 0; t < num; ++t) {
        const int e = permD[beg + t];
        acc += __bfloat162float(msg[(size_t)e*64 + c]);
    }
    const float agg = acc / fmaxf((float)num, 1.0f);
    const float* xr = X + (size_t)n * KIN;
    float r = 0.0f;
    #pragma unroll 16
    for (int i = 0; i < KIN; ++i) r = fmaf(xr[i], root[i*64 + c], r);
    float o = agg + r + bias[c];
    o = (o > 0.0f) ? o : expm1f(o);
    Xout[(size_t)n*64 + c] = o;
    if (Xbout) Xbout[(size_t)n*64 + c] = __float2bfloat16(o);
}

__global__ __launch_bounds__(256) void tail_kernel(
    const float* __restrict__ pos_skip, const int* __restrict__ batch_skip,
    float* __restrict__ out)
{
    const int i = blockIdx.x * 256 + threadIdx.x;
    if (i < NF*3) out[1048576 + i] = pos_skip[i];
    if (i < NF)   ((int*)out)[1048576 + NF*3 + i] = batch_skip[i];
}

extern "C" void kernel_launch(void* const* d_in, const int* in_sizes, int n_in,
                              void* d_out, int out_size, void* d_ws, size_t ws_size,
                              hipStream_t stream)
{
    const float* x          = (const float*)d_in[0];
    const float* pos        = (const float*)d_in[1];
    const int*   batch      = (const int*)d_in[2];
    const float* x_skip     = (const float*)d_in[3];
    const float* pos_skip   = (const float*)d_in[4];
    const int*   batch_skip = (const int*)d_in[5];
    const int*   ei         = (const int*)d_in[6];
    const float* W0    = (const float*)d_in[7];
    const float* root0 = (const float*)d_in[8];
    const float* b0    = (const float*)d_in[9];
    const float* W1    = (const float*)d_in[10];
    const float* root1 = (const float*)d_in[11];
    const float* b1    = (const float*)d_in[12];
    const float* W2    = (const float*)d_in[13];
    const float* root2 = (const float*)d_in[14];
    const float* b2    = (const float*)d_in[15];

    char* wp = (char*)d_ws;
    size_t used = 0;
    auto carve = [&](size_t bytes) {
        char* p = wp;
        size_t a = (bytes + 255) & ~(size_t)255;
        wp += a; used += a;
        return p;
    };
    float* X0    = (float*)carve((size_t)NF * 128 * 4);
    float* X1    = (float*)carve((size_t)NF * 64 * 4);
    float* X2    = (float*)carve((size_t)NF * 64 * 4);
    __hip_bfloat16* Xb0 = (__hip_bfloat16*)carve((size_t)NF * 128 * 2);
    __hip_bfloat16* Xb1 = (__hip_bfloat16*)carve((size_t)NF * 64 * 2);
    __hip_bfloat16* Xb2 = (__hip_bfloat16*)carve((size_t)NF * 64 * 2);
    __hip_bfloat16* Wt0 = (__hip_bfloat16*)carve((size_t)125 * 128 * 64 * 2);
    __hip_bfloat16* Wt1 = (__hip_bfloat16*)carve((size_t)125 * 64 * 64 * 2);
    __hip_bfloat16* Wt2 = (__hip_bfloat16*)carve((size_t)125 * 64 * 64 * 2);
    float* basis = (float*)carve((size_t)NE * 8 * 4);
    uint2* wi8   = (uint2*)carve((size_t)NE * 8);
    __hip_bfloat16* msg = (__hip_bfloat16*)carve((size_t)NE * 64 * 2);  // chunked path only
    int*   idx3  = (int*)carve((size_t)NF * 3 * 4);
    float* w3    = (float*)carve((size_t)NF * 3 * 4);
    int* zeroBase = (int*)carve((size_t)(NCELL + 3*NF) * 4);
    int* cellCnt  = zeroBase;
    int* cntD     = zeroBase + NCELL;
    int* cntS     = zeroBase + NCELL + NF;
    int* flags    = zeroBase + NCELL + 2*NF;
    int*   cellOffs   = (int*)carve((size_t)(NCELL+1) * 4);
    int*   cellCursor = (int*)carve((size_t)NCELL * 4);
    int*   cellId  = (int*)carve((size_t)NC * 4);
    int*   binPts  = (int*)carve((size_t)NC * 4);
    float4* binPB  = (float4*)carve((size_t)NC * 16);
    int*   offsD   = (int*)carve((size_t)(NF+1) * 4);
    int*   cursorD = (int*)carve((size_t)NF * 4);
    int*   permD   = (int*)carve((size_t)NE * 4);
    int*   offsS   = (int*)carve((size_t)(NF+1) * 4);
    int*   cursorS = (int*)carve((size_t)NF * 4);
    int*   permS   = (int*)carve((size_t)NE * 4);

    size_t remain = (ws_size > used) ? (ws_size - used) : 0;
    int CH = NF;
    while (CH > 512 && (size_t)CH * TROW * 2 > remain) CH >>= 1;
    const bool fullT = (CH == NF);
    __hip_bfloat16* T = (__hip_bfloat16*)wp;
    const int NCH = NF / CH;

    hipMemsetAsync(zeroBase, 0, (size_t)(NCELL + 3*NF) * 4, stream);
    // KNN via uniform grid (wave-per-query, exact + fallback)
    bin_hist_kernel<<<NC/256, 256, 0, stream>>>(pos, cellCnt, cellId);
    bin_scan_kernel<<<1, 512, 0, stream>>>(cellCnt, cellOffs, cellCursor);
    bin_scatter_kernel<<<NC/256, 256, 0, stream>>>(pos, batch, cellId, cellCursor, binPts, binPB);
    knn_wave_kernel<<<NF/4, 256, 0, stream>>>(binPB, binPts, cellOffs,
                                              pos_skip, batch_skip, idx3, w3, flags);
    knn_fallback_kernel<<<NF/4, 256, 0, stream>>>(pos, batch, pos_skip, batch_skip, flags, idx3, w3);
    interp_kernel<<<NF, 64, 0, stream>>>(x, x_skip, idx3, w3, X0, Xb0);
    // edge prep
    basis_kernel<<<NE/256, 256, 0, stream>>>(ei, pos_skip, basis, wi8, cntD, cntS);
    scan2_kernel<<<2, 1024, 0, stream>>>(cntD, offsD, cursorD, cntS, offsS, cursorS);
    scatter2_kernel<<<dim3(NE/256, 2), 256, 0, stream>>>(ei, cursorD, permD, cursorS, permS);
    wprep_all_kernel<<<dim3(125, 3), 256, 0, stream>>>(W0, W1, W2, Wt0, Wt1, Wt2);

    if (fullT) {
        gemm_mfma_kernel<128><<<dim3(125, NF/128), 256, 0, stream>>>(Xb0, Wt0, T);
        agg_fused_kernel<128><<<NF, 64, 0, stream>>>(T, basis, wi8, permD, offsD, cntD, ei,
                                                     X0, root0, b0, X1, Xb1, nullptr, nullptr);
        gemm_mfma_kernel<64><<<dim3(125, NF/128), 256, 0, stream>>>(Xb1, Wt1, T);
        agg_fused_kernel<64><<<NF, 64, 0, stream>>>(T, basis, wi8, permD, offsD, cntD, ei,
                                                    X1, root1, b1, X2, Xb2, nullptr, nullptr);
        gemm_mfma_kernel<64><<<dim3(125, NF/128), 256, 0, stream>>>(Xb2, Wt2, T);
        agg_fused_kernel<64><<<NF, 64, 0, stream>>>(T, basis, wi8, permD, offsD, cntD, ei,
                                                    X2, root2, b2, (float*)d_out, (__hip_bfloat16*)nullptr,
                                                    pos_skip, batch_skip);
    } else {
        for (int c = 0; c < NCH; ++c) {
            gemm_mfma_kernel<128><<<dim3(125, CH/128), 256, 0, stream>>>(Xb0 + (size_t)c*CH*128, Wt0, T);
            msg_kernel<<<2048, 256, 0, stream>>>(T, c*CH, basis, wi8, permS, offsS, c*CH, (c+1)*CH, ei, msg);
        }
        agg_msg_kernel<128><<<NF, 64, 0, stream>>>(msg, permD, offsD, cntD, X0, root0, b0, X1, Xb1);
        for (int c = 0; c < NCH; ++c) {
            gemm_mfma_kernel<64><<<dim3(125, CH/128), 256, 0, stream>>>(Xb1 + (size_t)c*CH*64, Wt1, T);
            msg_kernel<<<2048, 256, 0, stream>>>(T, c*CH, basis, wi8, permS, offsS, c*CH, (c+1)*CH, ei, msg);
        }
        agg_msg_kernel<64><<<NF, 64, 0, stream>>>(msg, permD, offsD, cntD, X1, root1, b1, X2, Xb2);
        for (int c = 0; c < NCH; ++c) {
            gemm_mfma_kernel<64><<<dim3(125, CH/128), 256, 0, stream>>>(Xb2 + (size_t)c*CH*64, Wt2, T);
            msg_kernel<<<2048, 256, 0, stream>>>(T, c*CH, basis, wi8, permS, offsS, c*CH, (c+1)*CH, ei, msg);
        }
        agg_msg_kernel<64><<<NF, 64, 0, stream>>>(msg, permD, offsD, cntD, X2, root2, b2, (float*)d_out, (__hip_bfloat16*)nullptr);
        tail_kernel<<<(NF*3 + 255)/256, 256, 0, stream>>>(pos_skip, batch_skip, (float*)d_out);
    }
}

// Round 11
// 592.521 us; speedup vs baseline: 1.5401x; 1.0703x over previous
//
#include <hip/hip_runtime.h>
#include <hip/hip_bf16.h>

#define NC 8192
#define NF 16384
#define NE 262144
#define GB 8
#define NCELL 512   // GB^3
#define CELLH 0.125f
#define NKC 75      // kerns per chunk (3 z-planes of 25)
#define TROWC 4800  // NKC * 64

typedef __attribute__((ext_vector_type(8))) short short8v;  // 8 bf16
typedef __attribute__((ext_vector_type(4))) float f32x4;

// ---------------- binning: histogram over coarse points ----------------
__global__ __launch_bounds__(256) void bin_hist_kernel(
    const float* __restrict__ pos, int* __restrict__ cellCnt, int* __restrict__ cellId)
{
    const int i = blockIdx.x * 256 + threadIdx.x;
    const int cx = min((int)(pos[i*3+0] * GB), GB-1);
    const int cy = min((int)(pos[i*3+1] * GB), GB-1);
    const int cz = min((int)(pos[i*3+2] * GB), GB-1);
    const int cell = (cz*GB + cy)*GB + cx;
    cellId[i] = cell;
    atomicAdd(&cellCnt[cell], 1);
}

// ---------------- binning: scan 512 cells (writes sentinel) ----------------
__global__ __launch_bounds__(512) void bin_scan_kernel(
    const int* __restrict__ cellCnt, int* __restrict__ cellOffs, int* __restrict__ cellCursor)
{
    __shared__ int s[512];
    const int tid = threadIdx.x;
    const int v = cellCnt[tid];
    s[tid] = v;
    __syncthreads();
    for (int off = 1; off < 512; off <<= 1) {
        int t = (tid >= off) ? s[tid - off] : 0;
        __syncthreads();
        s[tid] += t;
        __syncthreads();
    }
    cellOffs[tid] = s[tid] - v;
    cellCursor[tid] = s[tid] - v;
    if (tid == 511) cellOffs[512] = s[511];
}

// ---------------- binning: scatter points -> packed float4 (xyz + batch bits) ----------------
__global__ __launch_bounds__(256) void bin_scatter_kernel(
    const float* __restrict__ pos, const int* __restrict__ batch,
    const int* __restrict__ cellId, int* __restrict__ cellCursor,
    int* __restrict__ binPts, float4* __restrict__ binPB)
{
    const int i = blockIdx.x * 256 + threadIdx.x;
    const int cell = cellId[i];
    const int p = atomicAdd(&cellCursor[cell], 1);
    binPts[p] = i;
    float4 q;
    q.x = pos[i*3+0]; q.y = pos[i*3+1]; q.z = pos[i*3+2];
    q.w = __int_as_float(batch[i]);
    binPB[p] = q;
}

// ---------------- KNN: one wave per query, 9 contiguous ranges, no LDS ----------------
__global__ __launch_bounds__(256) void knn_wave_kernel(
    const float4* __restrict__ binPB, const int* __restrict__ binPts,
    const int* __restrict__ cellOffs,
    const float* __restrict__ pos_skip, const int* __restrict__ batch_skip,
    int* __restrict__ idx3, float* __restrict__ w3, int* __restrict__ flags)
{
    const int lane = threadIdx.x & 63;
    const int y = blockIdx.x * 4 + (threadIdx.x >> 6);
    const float px = pos_skip[y*3+0], py = pos_skip[y*3+1], pz = pos_skip[y*3+2];
    const int by = batch_skip[y];
    const int cx = min((int)(px * GB), GB-1);
    const int cy = min((int)(py * GB), GB-1);
    const int cz = min((int)(pz * GB), GB-1);
    const int xlo = max(cx-1,0), xhi = min(cx+1,GB-1);
    const int ylo = max(cy-1,0), yhi = min(cy+1,GB-1);
    const int zlo = max(cz-1,0), zhi = min(cz+1,GB-1);

    float b0 = INFINITY, b1 = INFINITY, b2 = INFINITY;
    int i0 = 0, i1 = 0, i2 = 0;
    auto ins = [&](float d, int gj) {
        if (d < b2) {
            if (d < b1) {
                b2 = b1; i2 = i1;
                if (d < b0) { b1 = b0; i1 = i0; b0 = d; i0 = gj; }
                else        { b1 = d;  i1 = gj; }
            } else { b2 = d; i2 = gj; }
        }
    };

    for (int zz = zlo; zz <= zhi; ++zz)
    for (int yy = ylo; yy <= yhi; ++yy) {
        const int rowb = (zz*GB + yy)*GB;
        const int b = cellOffs[rowb + xlo];
        const int e = cellOffs[rowb + xhi + 1];
        for (int p = b + lane; p < e; p += 64) {
            const float4 q = binPB[p];
            const float dx = px - q.x, dy = py - q.y, dz = pz - q.z;
            float d = dx*dx + dy*dy + dz*dz;
            if (__float_as_int(q.w) != by) d = INFINITY;
            ins(d, binPts[p]);
        }
    }
    #pragma unroll
    for (int mask = 1; mask <= 32; mask <<= 1) {
        float c0 = __shfl_xor(b0, mask), c1 = __shfl_xor(b1, mask), c2 = __shfl_xor(b2, mask);
        int   j0 = __shfl_xor(i0, mask), j1 = __shfl_xor(i1, mask), j2 = __shfl_xor(i2, mask);
        ins(c0, j0); ins(c1, j1); ins(c2, j2);
    }
    if (lane == 0) {
        float rd = 1e30f;
        if (cx > 0)    rd = fminf(rd, px - (cx-1)*CELLH);
        if (cx < GB-1) rd = fminf(rd, (cx+2)*CELLH - px);
        if (cy > 0)    rd = fminf(rd, py - (cy-1)*CELLH);
        if (cy < GB-1) rd = fminf(rd, (cy+2)*CELLH - py);
        if (cz > 0)    rd = fminf(rd, pz - (cz-1)*CELLH);
        if (cz < GB-1) rd = fminf(rd, (cz+2)*CELLH - pz);
        if (!(b2 <= rd*rd)) flags[y] = 1;
        idx3[y*3+0] = i0; idx3[y*3+1] = i1; idx3[y*3+2] = i2;
        w3[y*3+0] = 1.0f / fmaxf(b0, 1e-16f);
        w3[y*3+1] = 1.0f / fmaxf(b1, 1e-16f);
        w3[y*3+2] = 1.0f / fmaxf(b2, 1e-16f);
    }
}

// ---------------- KNN fallback: exact brute force for flagged queries ----------------
__global__ __launch_bounds__(256) void knn_fallback_kernel(
    const float* __restrict__ pos, const int* __restrict__ batch,
    const float* __restrict__ pos_skip, const int* __restrict__ batch_skip,
    const int* __restrict__ flags, int* __restrict__ idx3, float* __restrict__ w3)
{
    const int s = threadIdx.x & 63;
    const int y = blockIdx.x * 4 + (threadIdx.x >> 6);
    if (!flags[y]) return;
    const float px = pos_skip[y*3+0], py = pos_skip[y*3+1], pz = pos_skip[y*3+2];
    const int by = batch_skip[y];
    float b0 = INFINITY, b1 = INFINITY, b2 = INFINITY;
    int i0 = 0, i1 = 0, i2 = 0;
    auto ins = [&](float d, int gj) {
        if (d < b2) {
            if (d < b1) {
                b2 = b1; i2 = i1;
                if (d < b0) { b1 = b0; i1 = i0; b0 = d; i0 = gj; }
                else        { b1 = d;  i1 = gj; }
            } else { b2 = d; i2 = gj; }
        }
    };
    for (int j = s; j < NC; j += 64) {
        const float dx = px - pos[j*3+0];
        const float dy = py - pos[j*3+1];
        const float dz = pz - pos[j*3+2];
        float d = dx*dx + dy*dy + dz*dz;
        if (batch[j] != by) d = INFINITY;
        ins(d, j);
    }
    #pragma unroll
    for (int mask = 1; mask <= 32; mask <<= 1) {
        float c0 = __shfl_xor(b0, mask), c1 = __shfl_xor(b1, mask), c2 = __shfl_xor(b2, mask);
        int   j0 = __shfl_xor(i0, mask), j1 = __shfl_xor(i1, mask), j2 = __shfl_xor(i2, mask);
        ins(c0, j0); ins(c1, j1); ins(c2, j2);
    }
    if (s == 0) {
        idx3[y*3+0] = i0; idx3[y*3+1] = i1; idx3[y*3+2] = i2;
        w3[y*3+0] = 1.0f / fmaxf(b0, 1e-16f);
        w3[y*3+1] = 1.0f / fmaxf(b1, 1e-16f);
        w3[y*3+2] = 1.0f / fmaxf(b2, 1e-16f);
    }
}

// ---------------- interpolate + concat -> X0 fp32 + Xb0 bf16 ----------------
__global__ __launch_bounds__(64) void interp_kernel(
    const float* __restrict__ x, const float* __restrict__ x_skip,
    const int* __restrict__ idx3, const float* __restrict__ w3,
    float* __restrict__ X0, __hip_bfloat16* __restrict__ Xb0)
{
    const int n = blockIdx.x, c = threadIdx.x;
    const int j0 = idx3[n*3+0], j1 = idx3[n*3+1], j2 = idx3[n*3+2];
    const float w0 = w3[n*3+0], w1 = w3[n*3+1], w2 = w3[n*3+2];
    const float inv = 1.0f / (w0 + w1 + w2);
    const float h = (w0 * x[j0*64+c] + w1 * x[j1*64+c] + w2 * x[j2*64+c]) * inv;
    const float xs = x_skip[n*64+c];
    X0[(size_t)n*128 + c]      = h;
    X0[(size_t)n*128 + 64 + c] = xs;
    Xb0[(size_t)n*128 + c]      = __float2bfloat16(h);
    Xb0[(size_t)n*128 + 64 + c] = __float2bfloat16(xs);
}

// ---------------- spline basis per edge + bucketed dst histograms ----------------
// Bucket A: loz<2 (all 8 taps in kerns [0,75));  Bucket B: loz>=2 (taps in [50,125)).
__global__ __launch_bounds__(256) void basis_kernel(
    const int* __restrict__ ei, const float* __restrict__ pos_skip,
    float* __restrict__ basis, uint2* __restrict__ wi8,
    int* __restrict__ cntDA, int* __restrict__ cntDB)
{
    const int e = blockIdx.x * 256 + threadIdx.x;
    const int src = ei[e], dst = ei[NE + e];
    float fr[3]; int lo[3];
    #pragma unroll
    for (int d = 0; d < 3; ++d) {
        float p = (pos_skip[dst*3+d] - pos_skip[src*3+d]) * 4.0f + 0.5f;
        p = fminf(fmaxf(p, 0.0f), 1.0f);
        float v = p * 4.0f;
        float l = fminf(floorf(v), 3.0f);
        fr[d] = v - l;
        lo[d] = (int)l;
    }
    unsigned int wlo = 0, whi = 0;
    #pragma unroll
    for (int s = 0; s < 8; ++s) {
        const int bit0 = s & 1, bit1 = (s >> 1) & 1, bit2 = (s >> 2) & 1;
        float b = (bit0 ? fr[0] : 1.0f - fr[0])
                * (bit1 ? fr[1] : 1.0f - fr[1])
                * (bit2 ? fr[2] : 1.0f - fr[2]);
        int w = (lo[0] + bit0) + 5 * (lo[1] + bit1) + 25 * (lo[2] + bit2);
        basis[(size_t)e*8 + s] = b;
        if (s < 4) wlo |= ((unsigned)w) << (8*s);
        else       whi |= ((unsigned)w) << (8*(s-4));
    }
    wi8[e] = make_uint2(wlo, whi);
    if (lo[2] < 2) atomicAdd(&cntDA[dst], 1);
    else           atomicAdd(&cntDB[dst], 1);
}

// ---------------- dual exclusive scan over NF counts, single pass (16/thread) ----------------
__global__ __launch_bounds__(1024) void scan2_kernel(
    const int* __restrict__ cntA, int* __restrict__ offsA, int* __restrict__ curA,
    const int* __restrict__ cntB, int* __restrict__ offsB, int* __restrict__ curB)
{
    const int* cnt = blockIdx.x ? cntB : cntA;
    int* offs   = blockIdx.x ? offsB : offsA;
    int* cursor = blockIdx.x ? curB  : curA;
    __shared__ int s[1024];
    const int tid = threadIdx.x;
    const int base = tid * 16;
    int v[16];
    *(int4*)&v[0]  = *(const int4*)&cnt[base];
    *(int4*)&v[4]  = *(const int4*)&cnt[base+4];
    *(int4*)&v[8]  = *(const int4*)&cnt[base+8];
    *(int4*)&v[12] = *(const int4*)&cnt[base+12];
    int tsum = 0;
    #pragma unroll
    for (int j = 0; j < 16; ++j) tsum += v[j];
    s[tid] = tsum;
    __syncthreads();
    for (int off = 1; off < 1024; off <<= 1) {
        int t = (tid >= off) ? s[tid - off] : 0;
        __syncthreads();
        s[tid] += t;
        __syncthreads();
    }
    int run = s[tid] - tsum;
    #pragma unroll
    for (int j = 0; j < 16; ++j) { offs[base+j] = run; cursor[base+j] = run; run += v[j]; }
    if (tid == 1023) offs[NF] = run;
}

// ---------------- dual scatter into bucket lists (dst-sorted) ----------------
__global__ __launch_bounds__(256) void scatter2_kernel(
    const int* __restrict__ ei, const uint2* __restrict__ wi8,
    int* __restrict__ curA, int* __restrict__ permA,
    int* __restrict__ curB, int* __restrict__ permB)
{
    const int e = blockIdx.x * 256 + threadIdx.x;
    const bool bB = ((wi8[e].x & 255u) >= 50u);   // wk0 >= 50 <=> loz >= 2
    if (blockIdx.y == 0) {
        if (!bB) { const int p = atomicAdd(&curA[ei[NE + e]], 1); permA[p] = e; }
    } else {
        if (bB)  { const int p = atomicAdd(&curB[ei[NE + e]], 1); permB[p] = e; }
    }
}

// ---------------- W prep, all 3 layers: [125][KIN][64] fp32 -> [125][64][KIN] bf16 ----------------
__global__ __launch_bounds__(256) void wprep_all_kernel(
    const float* __restrict__ W0, const float* __restrict__ W1, const float* __restrict__ W2,
    __hip_bfloat16* __restrict__ Wt0, __hip_bfloat16* __restrict__ Wt1, __hip_bfloat16* __restrict__ Wt2)
{
    const int which = blockIdx.y;
    const float* W = (which == 0) ? W0 : (which == 1 ? W1 : W2);
    __hip_bfloat16* Wt = (which == 0) ? Wt0 : (which == 1 ? Wt1 : Wt2);
    const int KIN = (which == 0) ? 128 : 64;
    __shared__ float s[128*64];
    const int kern = blockIdx.x;
    const float* Wk = W + (size_t)kern * KIN * 64;
    for (int i = threadIdx.x; i < KIN*64; i += 256) s[i] = Wk[i];
    __syncthreads();
    const int nk8 = KIN/8;
    for (int i = threadIdx.x; i < 64*nk8; i += 256) {
        const int o = i / nk8, kb = (i % nk8) * 8;
        union { short8v v; __hip_bfloat16 h[8]; } u;
        #pragma unroll
        for (int j = 0; j < 8; ++j) u.h[j] = __float2bfloat16(s[(kb+j)*64 + o]);
        *(short8v*)&Wt[((size_t)kern*64 + o)*KIN + kb] = u.v;
    }
}

// ---------------- T chunk = Xb @ W[k0 .. k0+75) (bf16 MFMA, LDS-transposed epilogue) ----------------
template<int KIN>
__global__ __launch_bounds__(256) void gemm_chunk_kernel(
    const __hip_bfloat16* __restrict__ Xb,   // [NF][KIN] bf16
    const __hip_bfloat16* __restrict__ Wt,   // [125][64][KIN]
    __hip_bfloat16* __restrict__ T,          // [NF][TROWC] chunk
    int k0)
{
    constexpr int BKP = KIN + 8;
    __shared__ __hip_bfloat16 As[128*BKP];   // reused as C-tile [128][72]
    __shared__ __hip_bfloat16 Bs[64*BKP];
    const int kernL = blockIdx.x;            // 0..74 chunk-local
    const int kern  = k0 + kernL;
    const int m0    = blockIdx.y * 128;

    for (int i = threadIdx.x; i < 128*(KIN/8); i += 256) {
        const int r = i / (KIN/8), c8 = (i % (KIN/8)) * 8;
        *(short8v*)&As[r*BKP + c8] = *(const short8v*)&Xb[(size_t)(m0 + r)*KIN + c8];
    }
    const __hip_bfloat16* Wk = Wt + (size_t)kern * 64 * KIN;
    for (int i = threadIdx.x; i < 64*(KIN/8); i += 256) {
        const int r = i / (KIN/8), c8 = (i % (KIN/8)) * 8;
        *(short8v*)&Bs[r*BKP + c8] = *(const short8v*)&Wk[(size_t)r*KIN + c8];
    }
    __syncthreads();

    const int wid  = threadIdx.x >> 6;
    const int lane = threadIdx.x & 63;
    const int lr   = lane & 15;
    const int lk   = (lane >> 4) * 8;

    f32x4 acc[2][4] = {};
    #pragma unroll
    for (int ks = 0; ks < KIN/32; ++ks) {
        short8v a0 = *(const short8v*)&As[(wid*32 +      lr)*BKP + ks*32 + lk];
        short8v a1 = *(const short8v*)&As[(wid*32 + 16 + lr)*BKP + ks*32 + lk];
        #pragma unroll
        for (int n = 0; n < 4; ++n) {
            short8v b = *(const short8v*)&Bs[(n*16 + lr)*BKP + ks*32 + lk];
            acc[0][n] = __builtin_amdgcn_mfma_f32_16x16x32_bf16(a0, b, acc[0][n], 0, 0, 0);
            acc[1][n] = __builtin_amdgcn_mfma_f32_16x16x32_bf16(a1, b, acc[1][n], 0, 0, 0);
        }
    }

    __syncthreads();
    __hip_bfloat16* Ct = As;
    #pragma unroll
    for (int m = 0; m < 2; ++m) {
        const int rowL = wid*32 + m*16 + (lane >> 4)*4;
        #pragma unroll
        for (int n = 0; n < 4; ++n) {
            const int colL = n*16 + lr;
            #pragma unroll
            for (int i = 0; i < 4; ++i)
                Ct[(rowL + i)*72 + colL] = __float2bfloat16(acc[m][n][i]);
        }
    }
    __syncthreads();
    const size_t tbase = (size_t)m0 * TROWC + kernL*64;
    #pragma unroll
    for (int u = threadIdx.x; u < 1024; u += 256) {
        const int row = u >> 3, ch = (u & 7) * 8;
        *(short8v*)&T[tbase + (size_t)row*TROWC + ch] = *(short8v*)&Ct[row*72 + ch];
    }
}

// ---------------- bucketed agg: phase A writes partial acc; phase B finalizes ----------------
template<int KIN, bool FINAL>
__global__ __launch_bounds__(64) void agg_part_kernel(
    const __hip_bfloat16* __restrict__ T, const float* __restrict__ basis,
    const uint2* __restrict__ wi8, const int* __restrict__ perm,
    const int* __restrict__ offs, const int* __restrict__ cnt,
    const int* __restrict__ cntA, const int* __restrict__ cntB,
    const int* __restrict__ esrc, float* __restrict__ acc,
    const float* __restrict__ X, const float* __restrict__ root,
    const float* __restrict__ bias, float* __restrict__ Xout,
    __hip_bfloat16* __restrict__ Xbout,
    const float* __restrict__ tpos, const int* __restrict__ tbatch, int wkoff)
{
    const int n = blockIdx.x, c = threadIdx.x;
    float a = 0.0f;
    const int beg = offs[n], num = cnt[n];
    for (int t = 0; t < num; ++t) {
        const int e = perm[beg + t];
        const int src = esrc[e];
        const uint2 w8 = wi8[e];
        const float4 bl = *(const float4*)(basis + (size_t)e*8);
        const float4 bh = *(const float4*)(basis + (size_t)e*8 + 4);
        const __hip_bfloat16* Trow = T + (size_t)src * TROWC;
        a += bl.x * __bfloat162float(Trow[(((w8.x      ) & 255) - wkoff)*64 + c]);
        a += bl.y * __bfloat162float(Trow[(((w8.x >>  8) & 255) - wkoff)*64 + c]);
        a += bl.z * __bfloat162float(Trow[(((w8.x >> 16) & 255) - wkoff)*64 + c]);
        a += bl.w * __bfloat162float(Trow[(((w8.x >> 24) & 255) - wkoff)*64 + c]);
        a += bh.x * __bfloat162float(Trow[(((w8.y      ) & 255) - wkoff)*64 + c]);
        a += bh.y * __bfloat162float(Trow[(((w8.y >>  8) & 255) - wkoff)*64 + c]);
        a += bh.z * __bfloat162float(Trow[(((w8.y >> 16) & 255) - wkoff)*64 + c]);
        a += bh.w * __bfloat162float(Trow[(((w8.y >> 24) & 255) - wkoff)*64 + c]);
    }
    if (!FINAL) {
        acc[(size_t)n*64 + c] = a;
        return;
    }
    a += acc[(size_t)n*64 + c];
    const int numT = cntA[n] + cntB[n];
    const float agg = a / fmaxf((float)numT, 1.0f);
    const float* xr = X + (size_t)n * KIN;
    float r = 0.0f;
    #pragma unroll 16
    for (int i = 0; i < KIN; ++i) r = fmaf(xr[i], root[i*64 + c], r);
    float o = agg + r + bias[c];
    o = (o > 0.0f) ? o : expm1f(o);
    Xout[(size_t)n*64 + c] = o;
    if (Xbout) Xbout[(size_t)n*64 + c] = __float2bfloat16(o);
    if (tpos) {   // final layer: fold tail passthrough
        if (c < 3) Xout[1048576 + n*3 + c] = tpos[n*3 + c];
        if (c == 3) ((int*)Xout)[1048576 + NF*3 + n] = tbatch[n];
    }
}

extern "C" void kernel_launch(void* const* d_in, const int* in_sizes, int n_in,
                              void* d_out, int out_size, void* d_ws, size_t ws_size,
                              hipStream_t stream)
{
    const float* x          = (const float*)d_in[0];
    const float* pos        = (const float*)d_in[1];
    const int*   batch      = (const int*)d_in[2];
    const float* x_skip     = (const float*)d_in[3];
    const float* pos_skip   = (const float*)d_in[4];
    const int*   batch_skip = (const int*)d_in[5];
    const int*   ei         = (const int*)d_in[6];
    const float* W0    = (const float*)d_in[7];
    const float* root0 = (const float*)d_in[8];
    const float* b0    = (const float*)d_in[9];
    const float* W1    = (const float*)d_in[10];
    const float* root1 = (const float*)d_in[11];
    const float* b1    = (const float*)d_in[12];
    const float* W2    = (const float*)d_in[13];
    const float* root2 = (const float*)d_in[14];
    const float* b2    = (const float*)d_in[15];

    char* wp = (char*)d_ws;
    auto carve = [&](size_t bytes) {
        char* p = wp;
        wp += (bytes + 255) & ~(size_t)255;
        return p;
    };
    float* X0    = (float*)carve((size_t)NF * 128 * 4);
    float* X1    = (float*)carve((size_t)NF * 64 * 4);
    float* X2    = (float*)carve((size_t)NF * 64 * 4);
    __hip_bfloat16* Xb0 = (__hip_bfloat16*)carve((size_t)NF * 128 * 2);
    __hip_bfloat16* Xb1 = (__hip_bfloat16*)carve((size_t)NF * 64 * 2);
    __hip_bfloat16* Xb2 = (__hip_bfloat16*)carve((size_t)NF * 64 * 2);
    __hip_bfloat16* Wt0 = (__hip_bfloat16*)carve((size_t)125 * 128 * 64 * 2);
    __hip_bfloat16* Wt1 = (__hip_bfloat16*)carve((size_t)125 * 64 * 64 * 2);
    __hip_bfloat16* Wt2 = (__hip_bfloat16*)carve((size_t)125 * 64 * 64 * 2);
    float* basis = (float*)carve((size_t)NE * 8 * 4);
    uint2* wi8   = (uint2*)carve((size_t)NE * 8);
    float* acc   = (float*)carve((size_t)NF * 64 * 4);
    int*   idx3  = (int*)carve((size_t)NF * 3 * 4);
    float* w3    = (float*)carve((size_t)NF * 3 * 4);
    int* zeroBase = (int*)carve((size_t)(NCELL + 3*NF) * 4);
    int* cellCnt  = zeroBase;
    int* cntDA    = zeroBase + NCELL;
    int* cntDB    = zeroBase + NCELL + NF;
    int* flags    = zeroBase + NCELL + 2*NF;
    int*   cellOffs   = (int*)carve((size_t)(NCELL+1) * 4);
    int*   cellCursor = (int*)carve((size_t)NCELL * 4);
    int*   cellId  = (int*)carve((size_t)NC * 4);
    int*   binPts  = (int*)carve((size_t)NC * 4);
    float4* binPB  = (float4*)carve((size_t)NC * 16);
    int*   offsDA  = (int*)carve((size_t)(NF+1) * 4);
    int*   curDA   = (int*)carve((size_t)NF * 4);
    int*   permDA  = (int*)carve((size_t)NE * 4);
    int*   offsDB  = (int*)carve((size_t)(NF+1) * 4);
    int*   curDB   = (int*)carve((size_t)NF * 4);
    int*   permDB  = (int*)carve((size_t)NE * 4);
    __hip_bfloat16* T = (__hip_bfloat16*)carve((size_t)NF * TROWC * 2);  // 157 MB chunk

    hipMemsetAsync(zeroBase, 0, (size_t)(NCELL + 3*NF) * 4, stream);
    // KNN via uniform grid (wave-per-query, exact + fallback)
    bin_hist_kernel<<<NC/256, 256, 0, stream>>>(pos, cellCnt, cellId);
    bin_scan_kernel<<<1, 512, 0, stream>>>(cellCnt, cellOffs, cellCursor);
    bin_scatter_kernel<<<NC/256, 256, 0, stream>>>(pos, batch, cellId, cellCursor, binPts, binPB);
    knn_wave_kernel<<<NF/4, 256, 0, stream>>>(binPB, binPts, cellOffs,
                                              pos_skip, batch_skip, idx3, w3, flags);
    knn_fallback_kernel<<<NF/4, 256, 0, stream>>>(pos, batch, pos_skip, batch_skip, flags, idx3, w3);
    interp_kernel<<<NF, 64, 0, stream>>>(x, x_skip, idx3, w3, X0, Xb0);
    // edge prep (bucketed by kernel z-plane)
    basis_kernel<<<NE/256, 256, 0, stream>>>(ei, pos_skip, basis, wi8, cntDA, cntDB);
    scan2_kernel<<<2, 1024, 0, stream>>>(cntDA, offsDA, curDA, cntDB, offsDB, curDB);
    scatter2_kernel<<<dim3(NE/256, 2), 256, 0, stream>>>(ei, wi8, curDA, permDA, curDB, permDB);
    wprep_all_kernel<<<dim3(125, 3), 256, 0, stream>>>(W0, W1, W2, Wt0, Wt1, Wt2);

    // layer 0 (KIN=128)
    gemm_chunk_kernel<128><<<dim3(NKC, NF/128), 256, 0, stream>>>(Xb0, Wt0, T, 0);
    agg_part_kernel<128,false><<<NF, 64, 0, stream>>>(T, basis, wi8, permDA, offsDA, cntDA,
        cntDA, cntDB, ei, acc, nullptr, nullptr, nullptr, nullptr, nullptr, nullptr, nullptr, 0);
    gemm_chunk_kernel<128><<<dim3(NKC, NF/128), 256, 0, stream>>>(Xb0, Wt0, T, 50);
    agg_part_kernel<128,true><<<NF, 64, 0, stream>>>(T, basis, wi8, permDB, offsDB, cntDB,
        cntDA, cntDB, ei, acc, X0, root0, b0, X1, Xb1, nullptr, nullptr, 50);
    // layer 1 (KIN=64)
    gemm_chunk_kernel<64><<<dim3(NKC, NF/128), 256, 0, stream>>>(Xb1, Wt1, T, 0);
    agg_part_kernel<64,false><<<NF, 64, 0, stream>>>(T, basis, wi8, permDA, offsDA, cntDA,
        cntDA, cntDB, ei, acc, nullptr, nullptr, nullptr, nullptr, nullptr, nullptr, nullptr, 0);
    gemm_chunk_kernel<64><<<dim3(NKC, NF/128), 256, 0, stream>>>(Xb1, Wt1, T, 50);
    agg_part_kernel<64,true><<<NF, 64, 0, stream>>>(T, basis, wi8, permDB, offsDB, cntDB,
        cntDA, cntDB, ei, acc, X1, root1, b1, X2, Xb2, nullptr, nullptr, 50);
    // layer 2 (KIN=64) -> d_out (+tail)
    gemm_chunk_kernel<64><<<dim3(NKC, NF/128), 256, 0, stream>>>(Xb2, Wt2, T, 0);
    agg_part_kernel<64,false><<<NF, 64, 0, stream>>>(T, basis, wi8, permDA, offsDA, cntDA,
        cntDA, cntDB, ei, acc, nullptr, nullptr, nullptr, nullptr, nullptr, nullptr, nullptr, 0);
    gemm_chunk_kernel<64><<<dim3(NKC, NF/128), 256, 0, stream>>>(Xb2, Wt2, T, 50);
    agg_part_kernel<64,true><<<NF, 64, 0, stream>>>(T, basis, wi8, permDB, offsDB, cntDB,
        cntDA, cntDB, ei, acc, X2, root2, b2, (float*)d_out, (__hip_bfloat16*)nullptr,
        pos_skip, batch_skip, 50);
}